// Round 1
// baseline (554.843 us; speedup 1.0000x reference)
//
#include <hip/hip_runtime.h>
#include <math.h>

// Problem constants
#define NB 32
#define SS 64
#define EE 512
#define NH 4
#define HD 128
#define ROWS (NB*SS)          // 2048
#define L2T 13.544f
#define LNEPS 1e-5f

// ---------------------------------------------------------------------------
// Kernel 1: L2-distance attention + x1 = attn @ x  (writes x1_attn output and
// x_res[:, :512]).  One block per (b,f).
// ---------------------------------------------------------------------------
__global__ __launch_bounds__(256)
void l2attn_x1(const float* __restrict__ x, float* __restrict__ x1_attn,
               float* __restrict__ x_res) {
    const int f = blockIdx.x, b = blockIdx.y;
    const int tid = threadIdx.x, wave = tid >> 6, lane = tid & 63;
    __shared__ float d2s[64];
    __shared__ float attn_s[64];

    const float4* xb = (const float4*)(x + (size_t)b * SS * EE);  // row = 128 float4
    // this lane's slice of x[b,f,:]
    float4 xf0 = xb[f * 128 + lane * 2];
    float4 xf1 = xb[f * 128 + lane * 2 + 1];

    for (int g = wave; g < 64; g += 4) {
        float4 a0 = xb[g * 128 + lane * 2];
        float4 a1 = xb[g * 128 + lane * 2 + 1];
        float dx, s = 0.f;
        dx = a0.x - xf0.x; s += dx * dx;
        dx = a0.y - xf0.y; s += dx * dx;
        dx = a0.z - xf0.z; s += dx * dx;
        dx = a0.w - xf0.w; s += dx * dx;
        dx = a1.x - xf1.x; s += dx * dx;
        dx = a1.y - xf1.y; s += dx * dx;
        dx = a1.z - xf1.z; s += dx * dx;
        dx = a1.w - xf1.w; s += dx * dx;
        #pragma unroll
        for (int m = 32; m; m >>= 1) s += __shfl_xor(s, m);
        if (lane == 0) d2s[g] = s;
    }
    __syncthreads();

    if (tid < 64) {
        float v = -d2s[tid] * (1.0f / L2T);
        float mx = v;
        #pragma unroll
        for (int m = 32; m; m >>= 1) mx = fmaxf(mx, __shfl_xor(mx, m));
        float e = expf(v - mx);
        float sum = e;
        #pragma unroll
        for (int m = 32; m; m >>= 1) sum += __shfl_xor(sum, m);
        float a = e / sum;
        x1_attn[((size_t)b * SS + f) * SS + tid] = a;
        attn_s[tid] = a;
    }
    __syncthreads();

    // x1[b,f,e] = sum_g attn[g] * x[b,g,e]   (e = tid, tid+256)
    const float* xbf = x + (size_t)b * SS * EE;
    float acc0 = 0.f, acc1 = 0.f;
    #pragma unroll 8
    for (int g = 0; g < 64; ++g) {
        float ag = attn_s[g];
        acc0 += ag * xbf[g * EE + tid];
        acc1 += ag * xbf[g * EE + tid + 256];
    }
    float* dst = x_res + ((size_t)b * SS + f) * 1024;
    dst[tid] = acc0;
    dst[tid + 256] = acc1;
}

// ---------------------------------------------------------------------------
// Generic fp32 GEMM: C[M,N] = A[M,K] @ B[N,K]^T (+bias) (optional relu)
// 64x64 tile, BK=16, 256 threads, 4x4 per thread. All dims are multiples of
// the tile sizes for every call in this problem (no bounds checks).
// ---------------------------------------------------------------------------
template <bool RELU>
__global__ __launch_bounds__(256)
void gemm_bt(const float* __restrict__ A, int lda,
             const float* __restrict__ B, int ldb,
             const float* __restrict__ bias,
             float* __restrict__ C, int ldc, int K) {
    __shared__ float As[16][68];   // pad 68: conflict-free + 16B-aligned rows
    __shared__ float Bs[16][68];
    const int tid = threadIdx.x;
    const int tx = tid & 15, ty = tid >> 4;
    const int m0 = blockIdx.y * 64, n0 = blockIdx.x * 64;

    float acc[4][4] = {{0.f}};
    for (int k0 = 0; k0 < K; k0 += 16) {
        #pragma unroll
        for (int i = tid; i < 1024; i += 256) {
            int m = i >> 4, k = i & 15;
            As[k][m] = A[(size_t)(m0 + m) * lda + k0 + k];
            Bs[k][m] = B[(size_t)(n0 + m) * ldb + k0 + k];
        }
        __syncthreads();
        #pragma unroll
        for (int k = 0; k < 16; ++k) {
            float4 av = *(const float4*)&As[k][ty * 4];
            float4 bv = *(const float4*)&Bs[k][tx * 4];
            float a[4] = {av.x, av.y, av.z, av.w};
            float bb[4] = {bv.x, bv.y, bv.z, bv.w};
            #pragma unroll
            for (int i = 0; i < 4; ++i)
                #pragma unroll
                for (int j = 0; j < 4; ++j) acc[i][j] += a[i] * bb[j];
        }
        __syncthreads();
    }
    #pragma unroll
    for (int i = 0; i < 4; ++i) {
        size_t m = m0 + ty * 4 + i;
        #pragma unroll
        for (int j = 0; j < 4; ++j) {
            int n = n0 + tx * 4 + j;
            float v = acc[i][j] + (bias ? bias[n] : 0.f);
            if (RELU) v = fmaxf(v, 0.f);
            C[m * ldc + n] = v;
        }
    }
}

// ---------------------------------------------------------------------------
// Kernel 3: per-(b,h) attention. scores -> softmax (accumulate mean into
// x2_attn via atomics) -> o = a@v written to o_buf[(b,s), h*128+d].
// ---------------------------------------------------------------------------
__global__ __launch_bounds__(256)
void mha_attn(const float* __restrict__ qkv, float* __restrict__ o_buf,
              float* __restrict__ x2_attn) {
    const int h = blockIdx.x, b = blockIdx.y;
    const int tid = threadIdx.x, wave = tid >> 6, lane = tid & 63;
    __shared__ float kvs[64 * 129];   // k, later v (padded rows: conflict-free)
    __shared__ float sc[64 * 65];     // scores / probs

    const float* base = qkv + (size_t)b * SS * 1536;
    for (int i = tid; i < 64 * 128; i += 256) {
        int s = i >> 7, d = i & 127;
        kvs[s * 129 + d] = base[s * 1536 + 512 + h * 128 + d];
    }
    __syncthreads();

    const float scale = 0.08838834764831845f;  // 1/sqrt(128)
    // scores: wave handles rows f = wave, wave+4, ...; lane = g (k from LDS,
    // q row is wave-uniform -> scalar loads)
    for (int f = wave; f < 64; f += 4) {
        const float* qrow = base + f * 1536 + h * 128;
        float acc = 0.f;
        #pragma unroll 8
        for (int d = 0; d < 128; ++d) acc += qrow[d] * kvs[lane * 129 + d];
        sc[f * 65 + lane] = acc * scale;
    }
    __syncthreads();

    // softmax per row + accumulate head-mean
    for (int f = wave; f < 64; f += 4) {
        float v = sc[f * 65 + lane];
        float mx = v;
        #pragma unroll
        for (int m = 32; m; m >>= 1) mx = fmaxf(mx, __shfl_xor(mx, m));
        float e = expf(v - mx);
        float sum = e;
        #pragma unroll
        for (int m = 32; m; m >>= 1) sum += __shfl_xor(sum, m);
        float a = e / sum;
        sc[f * 65 + lane] = a;
        atomicAdd(&x2_attn[((size_t)b * SS + f) * SS + lane], 0.25f * a);
    }
    __syncthreads();

    // overwrite kvs with v
    for (int i = tid; i < 64 * 128; i += 256) {
        int s = i >> 7, d = i & 127;
        kvs[s * 129 + d] = base[s * 1536 + 1024 + h * 128 + d];
    }
    __syncthreads();

    // o[f,d] = sum_g a[f,g] * v[g,d]
    for (int p = tid; p < 64 * 128; p += 256) {
        int f = p >> 7, d = p & 127;
        float acc = 0.f;
        #pragma unroll 8
        for (int g = 0; g < 64; ++g) acc += sc[f * 65 + g] * kvs[g * 129 + d];
        o_buf[((size_t)b * SS + f) * EE + h * 128 + d] = acc;
    }
}

// ---------------------------------------------------------------------------
// Kernel 4: row-wise  out = LayerNorm(base + u) * g + be.  One block per row.
// ---------------------------------------------------------------------------
__global__ __launch_bounds__(256)
void add_ln(const float* __restrict__ base, const float* __restrict__ u,
            const float* __restrict__ gam, const float* __restrict__ bet,
            float* __restrict__ out) {
    const int row = blockIdx.x;
    const int tid = threadIdx.x, wave = tid >> 6, lane = tid & 63;
    const float* br = base + (size_t)row * EE;
    const float* ur = u + (size_t)row * EE;
    float t0 = br[tid] + ur[tid];
    float t1 = br[tid + 256] + ur[tid + 256];
    float s = t0 + t1, sq = t0 * t0 + t1 * t1;
    #pragma unroll
    for (int m = 32; m; m >>= 1) {
        s += __shfl_xor(s, m);
        sq += __shfl_xor(sq, m);
    }
    __shared__ float ssum[4], ssq[4];
    if (lane == 0) { ssum[wave] = s; ssq[wave] = sq; }
    __syncthreads();
    s = ssum[0] + ssum[1] + ssum[2] + ssum[3];
    sq = ssq[0] + ssq[1] + ssq[2] + ssq[3];
    float mean = s * (1.0f / EE);
    float var = sq * (1.0f / EE) - mean * mean;
    float inv = rsqrtf(var + LNEPS);
    float* orow = out + (size_t)row * EE;
    orow[tid] = (t0 - mean) * inv * gam[tid] + bet[tid];
    orow[tid + 256] = (t1 - mean) * inv * gam[tid + 256] + bet[tid + 256];
}

// ---------------------------------------------------------------------------
// Kernel 5: pair MLPs via projection trick.
// h[b,f,g,c] = relu(attn[b,f,g]*(P[b,g,c]-P[b,f,c]) + b1[c])
// out[b,f,g] = relu(sum_c w2[c]*h + b2)
// One block per (b,f); wave handles g's, lane covers 2 channels.
// ---------------------------------------------------------------------------
__global__ __launch_bounds__(256)
void pair_mlp(const float* __restrict__ P1, const float* __restrict__ P2,
              const float* __restrict__ a1, const float* __restrict__ a2,
              const float* __restrict__ d1b1, const float* __restrict__ d1w2,
              const float* __restrict__ d1b2, const float* __restrict__ d2b1,
              const float* __restrict__ d2w2, const float* __restrict__ d2b2,
              float* __restrict__ out1, float* __restrict__ out2) {
    const int f = blockIdx.x, b = blockIdx.y;
    const int tid = threadIdx.x, wave = tid >> 6, lane = tid & 63;
    const size_t row = (size_t)b * SS + f;
    const int c0 = lane * 2, c1 = lane * 2 + 1;

    const float p1f0 = P1[row * 128 + c0], p1f1 = P1[row * 128 + c1];
    const float p2f0 = P2[row * 128 + c0], p2f1 = P2[row * 128 + c1];
    const float w10 = d1w2[c0], w11 = d1w2[c1];
    const float w20 = d2w2[c0], w21 = d2w2[c1];
    const float b10 = d1b1[c0], b11 = d1b1[c1];
    const float b20 = d2b1[c0], b21 = d2b1[c1];
    const float bb1 = d1b2[0], bb2 = d2b2[0];

    const float* a1r = a1 + row * SS;
    const float* a2r = a2 + row * SS;
    const size_t bbase = (size_t)b * SS * 128;

    for (int g = wave; g < 64; g += 4) {
        float aa1 = a1r[g], aa2 = a2r[g];
        float q10 = P1[bbase + g * 128 + c0], q11 = P1[bbase + g * 128 + c1];
        float q20 = P2[bbase + g * 128 + c0], q21 = P2[bbase + g * 128 + c1];
        float h10 = fmaxf(aa1 * (q10 - p1f0) + b10, 0.f);
        float h11 = fmaxf(aa1 * (q11 - p1f1) + b11, 0.f);
        float h20 = fmaxf(aa2 * (q20 - p2f0) + b20, 0.f);
        float h21 = fmaxf(aa2 * (q21 - p2f1) + b21, 0.f);
        float s1 = w10 * h10 + w11 * h11;
        float s2 = w20 * h20 + w21 * h21;
        #pragma unroll
        for (int m = 32; m; m >>= 1) {
            s1 += __shfl_xor(s1, m);
            s2 += __shfl_xor(s2, m);
        }
        if (lane == 0) {
            out1[row * SS + g] = fmaxf(s1 + bb1, 0.f);
            out2[row * SS + g] = fmaxf(s2 + bb2, 0.f);
        }
    }
}

// ---------------------------------------------------------------------------
extern "C" void kernel_launch(void* const* d_in, const int* in_sizes, int n_in,
                              void* d_out, int out_size, void* d_ws,
                              size_t ws_size, hipStream_t stream) {
    const float* x    = (const float*)d_in[0];
    const float* Wqkv = (const float*)d_in[1];
    const float* bqkv = (const float*)d_in[2];
    const float* Wo   = (const float*)d_in[3];
    const float* bo   = (const float*)d_in[4];
    const float* W1   = (const float*)d_in[5];
    const float* b1   = (const float*)d_in[6];
    const float* W2   = (const float*)d_in[7];
    const float* b2   = (const float*)d_in[8];
    const float* g1   = (const float*)d_in[9];
    const float* be1  = (const float*)d_in[10];
    const float* g2   = (const float*)d_in[11];
    const float* be2  = (const float*)d_in[12];
    const float* d1W1 = (const float*)d_in[13];
    const float* d1b1 = (const float*)d_in[14];
    const float* d1W2 = (const float*)d_in[15];
    const float* d1b2 = (const float*)d_in[16];
    const float* d2W1 = (const float*)d_in[17];
    const float* d2b1 = (const float*)d_in[18];
    const float* d2W2 = (const float*)d_in[19];
    const float* d2b2 = (const float*)d_in[20];

    float* out      = (float*)d_out;
    float* out_main = out;                         // 32*64*512
    float* x1_attn  = out + 1048576;               // 32*64*64
    float* x2_attn  = out + 1048576 + 131072;
    float* diff1    = out + 1048576 + 2 * 131072;
    float* diff2    = out + 1048576 + 3 * 131072;

    float* ws    = (float*)d_ws;
    float* qkv   = ws;                  // 2048*1536
    float* x_res = qkv + 3145728;       // 2048*1024
    float* o_buf = x_res + 2097152;     // 2048*512
    float* u_buf = o_buf + 1048576;     // 2048*512
    float* h_buf = u_buf + 1048576;     // 2048*512
    float* P1    = h_buf + 1048576;     // 2048*128
    float* P2    = P1 + 262144;         // 2048*128

    // x2_attn accumulated via atomics -> zero it (workspace is poisoned 0xAA)
    hipMemsetAsync(x2_attn, 0, 131072 * sizeof(float), stream);

    // L2 attention + x1 -> x_res[:, :512] and x1_attn output
    l2attn_x1<<<dim3(64, 32), 256, 0, stream>>>(x, x1_attn, x_res);

    // qkv = x @ Wqkv^T + bqkv : M=2048 N=1536 K=512
    gemm_bt<false><<<dim3(24, 32), 256, 0, stream>>>(x, 512, Wqkv, 512, bqkv,
                                                     qkv, 1536, 512);
    // attention per (b,h)
    mha_attn<<<dim3(4, 32), 256, 0, stream>>>(qkv, o_buf, x2_attn);

    // x_res[:, 512:] = o @ Wo^T + bo : M=2048 N=512 K=512
    gemm_bt<false><<<dim3(8, 32), 256, 0, stream>>>(o_buf, 512, Wo, 512, bo,
                                                    x_res + 512, 1024, 512);
    // u = relu(x_res @ W1^T + b1) : K=1024
    gemm_bt<true><<<dim3(8, 32), 256, 0, stream>>>(x_res, 1024, W1, 1024, b1,
                                                   u_buf, 512, 1024);
    // h = LN(x + u)
    add_ln<<<2048, 256, 0, stream>>>(x, u_buf, g1, be1, h_buf);
    // u = relu(h @ W2^T + b2) : K=512
    gemm_bt<true><<<dim3(8, 32), 256, 0, stream>>>(h_buf, 512, W2, 512, b2,
                                                   u_buf, 512, 512);
    // out = LN(h + u)
    add_ln<<<2048, 256, 0, stream>>>(h_buf, u_buf, g2, be2, out_main);

    // P1 = x @ d1W1^T, P2 = x @ d2W1^T : M=2048 N=128 K=512
    gemm_bt<false><<<dim3(2, 32), 256, 0, stream>>>(x, 512, d1W1, 512, nullptr,
                                                    P1, 128, 512);
    gemm_bt<false><<<dim3(2, 32), 256, 0, stream>>>(x, 512, d2W1, 512, nullptr,
                                                    P2, 128, 512);
    // pair MLPs
    pair_mlp<<<dim3(64, 32), 256, 0, stream>>>(P1, P2, x1_attn, x2_attn, d1b1,
                                               d1W2, d1b2, d2b1, d2W2, d2b2,
                                               diff1, diff2);
}

// Round 2
// 286.397 us; speedup vs baseline: 1.9373x; 1.9373x over previous
//
#include <hip/hip_runtime.h>
#include <math.h>

// Problem constants
#define NB 32
#define SS 64
#define EE 512
#define L2T 13.544f
#define LNEPS 1e-5f

using bf16x8 = __attribute__((ext_vector_type(8))) __bf16;
using f32x4  = __attribute__((ext_vector_type(4))) float;

typedef const void __attribute__((address_space(1))) cv_global;
typedef void __attribute__((address_space(3))) v_lds;

__device__ inline unsigned short f2bf(float f) {
    union { float f; unsigned u; } v; v.f = f;
    unsigned r = v.u + 0x7fff + ((v.u >> 16) & 1);
    return (unsigned short)(r >> 16);
}
__device__ inline float bf2f(unsigned short h) {
    union { unsigned u; float f; } v; v.u = (unsigned)h << 16;
    return v.f;
}

// ---------------------------------------------------------------------------
// Convert x + all weights to bf16 into one contiguous region.
// Offsets (ushort elems): xb@0 (1048576), Wqkv@1048576 (786432),
// Wo@1835008 (262144), W1@2097152 (524288), W2@2621440 (262144),
// d1W1@2883584 (65536), d2W1@2949120 (65536). Total 3014656.
// ---------------------------------------------------------------------------
__global__ __launch_bounds__(256)
void convert_all(const float* __restrict__ x, const float* __restrict__ Wqkv,
                 const float* __restrict__ Wo, const float* __restrict__ W1,
                 const float* __restrict__ W2, const float* __restrict__ d1,
                 const float* __restrict__ d2, unsigned short* __restrict__ dst) {
    int i = blockIdx.x * 256 + threadIdx.x;
    const float* s; int off;
    if (i < 1048576)      { s = x;    off = 0; }
    else if (i < 1835008) { s = Wqkv; off = 1048576; }
    else if (i < 2097152) { s = Wo;   off = 1835008; }
    else if (i < 2621440) { s = W1;   off = 2097152; }
    else if (i < 2883584) { s = W2;   off = 2621440; }
    else if (i < 2949120) { s = d1;   off = 2883584; }
    else                  { s = d2;   off = 2949120; }
    dst[i] = f2bf(s[i - off]);
}

// ---------------------------------------------------------------------------
// Kernel 1: L2-distance attention (fp32 path — precision critical) + x1 write
// as bf16 into x_resb[:, :512]. One block per (b,f).
// ---------------------------------------------------------------------------
__global__ __launch_bounds__(256)
void l2attn_x1(const float* __restrict__ x, float* __restrict__ x1_attn,
               unsigned short* __restrict__ x_resb) {
    const int f = blockIdx.x, b = blockIdx.y;
    const int tid = threadIdx.x, wave = tid >> 6, lane = tid & 63;
    __shared__ float d2s[64];
    __shared__ float attn_s[64];

    const float4* xb = (const float4*)(x + (size_t)b * SS * EE);
    float4 xf0 = xb[f * 128 + lane * 2];
    float4 xf1 = xb[f * 128 + lane * 2 + 1];

    for (int g = wave; g < 64; g += 4) {
        float4 a0 = xb[g * 128 + lane * 2];
        float4 a1 = xb[g * 128 + lane * 2 + 1];
        float dx, s = 0.f;
        dx = a0.x - xf0.x; s += dx * dx;
        dx = a0.y - xf0.y; s += dx * dx;
        dx = a0.z - xf0.z; s += dx * dx;
        dx = a0.w - xf0.w; s += dx * dx;
        dx = a1.x - xf1.x; s += dx * dx;
        dx = a1.y - xf1.y; s += dx * dx;
        dx = a1.z - xf1.z; s += dx * dx;
        dx = a1.w - xf1.w; s += dx * dx;
        #pragma unroll
        for (int m = 32; m; m >>= 1) s += __shfl_xor(s, m);
        if (lane == 0) d2s[g] = s;
    }
    __syncthreads();

    if (tid < 64) {
        float v = -d2s[tid] * (1.0f / L2T);
        float mx = v;
        #pragma unroll
        for (int m = 32; m; m >>= 1) mx = fmaxf(mx, __shfl_xor(mx, m));
        float e = expf(v - mx);
        float sum = e;
        #pragma unroll
        for (int m = 32; m; m >>= 1) sum += __shfl_xor(sum, m);
        float a = e / sum;
        x1_attn[((size_t)b * SS + f) * SS + tid] = a;
        attn_s[tid] = a;
    }
    __syncthreads();

    const float* xbf = x + (size_t)b * SS * EE;
    float acc0 = 0.f, acc1 = 0.f;
    #pragma unroll 8
    for (int g = 0; g < 64; ++g) {
        float ag = attn_s[g];
        acc0 += ag * xbf[g * EE + tid];
        acc1 += ag * xbf[g * EE + tid + 256];
    }
    unsigned short* dst = x_resb + ((size_t)b * SS + f) * 1024;
    dst[tid] = f2bf(acc0);
    dst[tid + 256] = f2bf(acc1);
}

// ---------------------------------------------------------------------------
// bf16 MFMA GEMM: C[M,N] = A[M,K] @ B[N,K]^T (+bias)(+relu), out fp32 or bf16.
// BM=BN=64, BK=32, 256 threads = 4 waves, each wave a 32x32 quadrant via
// 2x2 of mfma_f32_16x16x32_bf16. global_load_lds width=16 staging.
// ---------------------------------------------------------------------------
template <bool RELU, bool OUTBF16>
__global__ __launch_bounds__(256)
void gemm_mfma(const unsigned short* __restrict__ A, int lda,
               const unsigned short* __restrict__ B, int ldb,
               const float* __restrict__ bias, float* __restrict__ Cf,
               unsigned short* __restrict__ Cb, int ldc, int K) {
    __shared__ unsigned short Asl[64 * 32];
    __shared__ unsigned short Bsl[64 * 32];
    const int tid = threadIdx.x;
    const int wave = tid >> 6, lane = tid & 63;
    const int m0 = blockIdx.y * 64, n0 = blockIdx.x * 64;
    const int wm = (wave >> 1) * 32, wn = (wave & 1) * 32;

    f32x4 acc00 = {0.f, 0.f, 0.f, 0.f};
    f32x4 acc01 = acc00, acc10 = acc00, acc11 = acc00;

    // staging: thread i covers row i>>2, bf16 cols (i&3)*8 .. +7 (16B)
    const int srow = tid >> 2, scol = (tid & 3) * 8;
    const unsigned short* Ag = A + (size_t)(m0 + srow) * lda + scol;
    const unsigned short* Bg = B + (size_t)(n0 + srow) * ldb + scol;
    v_lds* AslW = (v_lds*)(Asl + wave * 512);   // wave-uniform LDS base
    v_lds* BslW = (v_lds*)(Bsl + wave * 512);

    const int fr = lane & 15;          // row within 16-tile
    const int kq = (lane >> 4) * 8;    // k quad offset

    for (int k0 = 0; k0 < K; k0 += 32) {
        __builtin_amdgcn_global_load_lds((cv_global*)(Ag + k0), AslW, 16, 0, 0);
        __builtin_amdgcn_global_load_lds((cv_global*)(Bg + k0), BslW, 16, 0, 0);
        __syncthreads();
        bf16x8 a0 = *(const bf16x8*)(Asl + (wm + fr) * 32 + kq);
        bf16x8 a1 = *(const bf16x8*)(Asl + (wm + 16 + fr) * 32 + kq);
        bf16x8 b0 = *(const bf16x8*)(Bsl + (wn + fr) * 32 + kq);
        bf16x8 b1 = *(const bf16x8*)(Bsl + (wn + 16 + fr) * 32 + kq);
        acc00 = __builtin_amdgcn_mfma_f32_16x16x32_bf16(a0, b0, acc00, 0, 0, 0);
        acc01 = __builtin_amdgcn_mfma_f32_16x16x32_bf16(a0, b1, acc01, 0, 0, 0);
        acc10 = __builtin_amdgcn_mfma_f32_16x16x32_bf16(a1, b0, acc10, 0, 0, 0);
        acc11 = __builtin_amdgcn_mfma_f32_16x16x32_bf16(a1, b1, acc11, 0, 0, 0);
        __syncthreads();
    }

    // C/D layout: col = lane&15, row = (lane>>4)*4 + reg   [m89/m91 verified]
    const int crow = (lane >> 4) * 4, ccol = lane & 15;
    float bj0 = bias ? bias[n0 + wn + ccol] : 0.f;
    float bj1 = bias ? bias[n0 + wn + 16 + ccol] : 0.f;

    auto store_tile = [&](f32x4 acc, int mt, int nt, float bj) {
        #pragma unroll
        for (int r = 0; r < 4; ++r) {
            size_t m = (size_t)(m0 + mt + crow + r);
            int n = n0 + nt + ccol;
            float v = acc[r] + bj;
            if (RELU) v = fmaxf(v, 0.f);
            if (OUTBF16) Cb[m * ldc + n] = f2bf(v);
            else         Cf[m * ldc + n] = v;
        }
    };
    store_tile(acc00, wm,      wn,      bj0);
    store_tile(acc01, wm,      wn + 16, bj1);
    store_tile(acc10, wm + 16, wn,      bj0);
    store_tile(acc11, wm + 16, wn + 16, bj1);
}

// ---------------------------------------------------------------------------
// Kernel 3: per-(b,h) attention on bf16 qkv. Writes o (bf16) + x2_attn mean.
// ---------------------------------------------------------------------------
__global__ __launch_bounds__(256)
void mha_attn(const unsigned short* __restrict__ qkv,
              unsigned short* __restrict__ o_buf, float* __restrict__ x2_attn) {
    const int h = blockIdx.x, b = blockIdx.y;
    const int tid = threadIdx.x, wave = tid >> 6, lane = tid & 63;
    __shared__ float kvs[64 * 129];
    __shared__ float sc[64 * 65];

    const unsigned short* base = qkv + (size_t)b * SS * 1536;
    for (int i = tid; i < 64 * 128; i += 256) {
        int s = i >> 7, d = i & 127;
        kvs[s * 129 + d] = bf2f(base[s * 1536 + 512 + h * 128 + d]);
    }
    __syncthreads();

    const float scale = 0.08838834764831845f;  // 1/sqrt(128)
    for (int f = wave; f < 64; f += 4) {
        const unsigned short* qrow = base + f * 1536 + h * 128;
        float acc = 0.f;
        #pragma unroll 8
        for (int d = 0; d < 128; ++d) acc += bf2f(qrow[d]) * kvs[lane * 129 + d];
        sc[f * 65 + lane] = acc * scale;
    }
    __syncthreads();

    for (int f = wave; f < 64; f += 4) {
        float v = sc[f * 65 + lane];
        float mx = v;
        #pragma unroll
        for (int m = 32; m; m >>= 1) mx = fmaxf(mx, __shfl_xor(mx, m));
        float e = expf(v - mx);
        float sum = e;
        #pragma unroll
        for (int m = 32; m; m >>= 1) sum += __shfl_xor(sum, m);
        float a = e / sum;
        sc[f * 65 + lane] = a;
        atomicAdd(&x2_attn[((size_t)b * SS + f) * SS + lane], 0.25f * a);
    }
    __syncthreads();

    for (int i = tid; i < 64 * 128; i += 256) {
        int s = i >> 7, d = i & 127;
        kvs[s * 129 + d] = bf2f(base[s * 1536 + 1024 + h * 128 + d]);
    }
    __syncthreads();

    for (int p = tid; p < 64 * 128; p += 256) {
        int f = p >> 7, d = p & 127;
        float acc = 0.f;
        #pragma unroll 8
        for (int g = 0; g < 64; ++g) acc += sc[f * 65 + g] * kvs[g * 129 + d];
        o_buf[((size_t)b * SS + f) * EE + h * 128 + d] = f2bf(acc);
    }
}

// ---------------------------------------------------------------------------
// Kernel 4: out = LayerNorm(base + u) * g + be (+ optional bf16 copy).
// ---------------------------------------------------------------------------
__global__ __launch_bounds__(256)
void add_ln(const float* __restrict__ base, const float* __restrict__ u,
            const float* __restrict__ gam, const float* __restrict__ bet,
            float* __restrict__ out, unsigned short* __restrict__ outb) {
    const int row = blockIdx.x;
    const int tid = threadIdx.x, wave = tid >> 6, lane = tid & 63;
    const float* br = base + (size_t)row * EE;
    const float* ur = u + (size_t)row * EE;
    float t0 = br[tid] + ur[tid];
    float t1 = br[tid + 256] + ur[tid + 256];
    float s = t0 + t1, sq = t0 * t0 + t1 * t1;
    #pragma unroll
    for (int m = 32; m; m >>= 1) {
        s += __shfl_xor(s, m);
        sq += __shfl_xor(sq, m);
    }
    __shared__ float ssum[4], ssq[4];
    if (lane == 0) { ssum[wave] = s; ssq[wave] = sq; }
    __syncthreads();
    s = ssum[0] + ssum[1] + ssum[2] + ssum[3];
    sq = ssq[0] + ssq[1] + ssq[2] + ssq[3];
    float mean = s * (1.0f / EE);
    float var = sq * (1.0f / EE) - mean * mean;
    float inv = rsqrtf(var + LNEPS);
    float v0 = (t0 - mean) * inv * gam[tid] + bet[tid];
    float v1 = (t1 - mean) * inv * gam[tid + 256] + bet[tid + 256];
    float* orow = out + (size_t)row * EE;
    orow[tid] = v0;
    orow[tid + 256] = v1;
    if (outb) {
        unsigned short* obr = outb + (size_t)row * EE;
        obr[tid] = f2bf(v0);
        obr[tid + 256] = f2bf(v1);
    }
}

// ---------------------------------------------------------------------------
// Kernel 5: pair MLPs via projection trick. P[row][0:128]=P1, [128:256]=P2.
// ---------------------------------------------------------------------------
__global__ __launch_bounds__(256)
void pair_mlp(const float* __restrict__ P, const float* __restrict__ a1,
              const float* __restrict__ a2, const float* __restrict__ d1b1,
              const float* __restrict__ d1w2, const float* __restrict__ d1b2,
              const float* __restrict__ d2b1, const float* __restrict__ d2w2,
              const float* __restrict__ d2b2, float* __restrict__ out1,
              float* __restrict__ out2) {
    const int f = blockIdx.x, b = blockIdx.y;
    const int tid = threadIdx.x, wave = tid >> 6, lane = tid & 63;
    const size_t row = (size_t)b * SS + f;
    const int c0 = lane * 2, c1 = lane * 2 + 1;

    const float p1f0 = P[row * 256 + c0],       p1f1 = P[row * 256 + c1];
    const float p2f0 = P[row * 256 + 128 + c0], p2f1 = P[row * 256 + 128 + c1];
    const float w10 = d1w2[c0], w11 = d1w2[c1];
    const float w20 = d2w2[c0], w21 = d2w2[c1];
    const float b10 = d1b1[c0], b11 = d1b1[c1];
    const float b20 = d2b1[c0], b21 = d2b1[c1];
    const float bb1 = d1b2[0], bb2 = d2b2[0];

    const float* a1r = a1 + row * SS;
    const float* a2r = a2 + row * SS;
    const size_t bbase = (size_t)b * SS * 256;

    for (int g = wave; g < 64; g += 4) {
        float aa1 = a1r[g], aa2 = a2r[g];
        float q10 = P[bbase + g * 256 + c0],       q11 = P[bbase + g * 256 + c1];
        float q20 = P[bbase + g * 256 + 128 + c0], q21 = P[bbase + g * 256 + 128 + c1];
        float h10 = fmaxf(aa1 * (q10 - p1f0) + b10, 0.f);
        float h11 = fmaxf(aa1 * (q11 - p1f1) + b11, 0.f);
        float h20 = fmaxf(aa2 * (q20 - p2f0) + b20, 0.f);
        float h21 = fmaxf(aa2 * (q21 - p2f1) + b21, 0.f);
        float s1 = w10 * h10 + w11 * h11;
        float s2 = w20 * h20 + w21 * h21;
        #pragma unroll
        for (int m = 32; m; m >>= 1) {
            s1 += __shfl_xor(s1, m);
            s2 += __shfl_xor(s2, m);
        }
        if (lane == 0) {
            out1[row * SS + g] = fmaxf(s1 + bb1, 0.f);
            out2[row * SS + g] = fmaxf(s2 + bb2, 0.f);
        }
    }
}

// ---------------------------------------------------------------------------
extern "C" void kernel_launch(void* const* d_in, const int* in_sizes, int n_in,
                              void* d_out, int out_size, void* d_ws,
                              size_t ws_size, hipStream_t stream) {
    const float* x    = (const float*)d_in[0];
    const float* Wqkv = (const float*)d_in[1];
    const float* bqkv = (const float*)d_in[2];
    const float* Wo   = (const float*)d_in[3];
    const float* bo   = (const float*)d_in[4];
    const float* W1   = (const float*)d_in[5];
    const float* b1   = (const float*)d_in[6];
    const float* W2   = (const float*)d_in[7];
    const float* b2   = (const float*)d_in[8];
    const float* g1   = (const float*)d_in[9];
    const float* be1  = (const float*)d_in[10];
    const float* g2   = (const float*)d_in[11];
    const float* be2  = (const float*)d_in[12];
    const float* d1W1 = (const float*)d_in[13];
    const float* d1b1 = (const float*)d_in[14];
    const float* d1W2 = (const float*)d_in[15];
    const float* d1b2 = (const float*)d_in[16];
    const float* d2W1 = (const float*)d_in[17];
    const float* d2b1 = (const float*)d_in[18];
    const float* d2W2 = (const float*)d_in[19];
    const float* d2b2 = (const float*)d_in[20];

    float* out      = (float*)d_out;
    float* out_main = out;                         // 32*64*512
    float* x1_attn  = out + 1048576;               // 32*64*64
    float* x2_attn  = out + 1048576 + 131072;
    float* diff1    = out + 1048576 + 2 * 131072;
    float* diff2    = out + 1048576 + 3 * 131072;

    // fp32 workspace
    float* ws    = (float*)d_ws;
    float* u_buf = ws;                  // 2048*512
    float* h_buf = u_buf + 1048576;     // 2048*512
    float* P     = h_buf + 1048576;     // 2048*256
    // bf16 workspace
    unsigned short* bb    = (unsigned short*)(P + 524288);
    unsigned short* xb    = bb;                   // 2048*512
    unsigned short* Wqkvb = bb + 1048576;         // 1536*512
    unsigned short* Wob   = bb + 1835008;         // 512*512
    unsigned short* W1b   = bb + 2097152;         // 512*1024
    unsigned short* W2b   = bb + 2621440;         // 512*512
    unsigned short* Wpb   = bb + 2883584;         // 256*512 (d1W1 ++ d2W1)
    unsigned short* qkvb  = bb + 3014656;         // 2048*1536
    unsigned short* ob    = bb + 6160384;         // 2048*512
    unsigned short* x_resb= bb + 7208960;         // 2048*1024
    unsigned short* hb    = bb + 9306112;         // 2048*512

    hipMemsetAsync(x2_attn, 0, 131072 * sizeof(float), stream);

    convert_all<<<11776, 256, 0, stream>>>(x, Wqkv, Wo, W1, W2, d1W1, d2W1, bb);

    // L2 attention + x1 -> x1_attn (f32 out) and x_resb[:, :512] (bf16)
    l2attn_x1<<<dim3(64, 32), 256, 0, stream>>>(x, x1_attn, x_resb);

    // qkv = x @ Wqkv^T + bqkv -> bf16 : M=2048 N=1536 K=512
    gemm_mfma<false, true><<<dim3(24, 32), 256, 0, stream>>>(
        xb, 512, Wqkvb, 512, bqkv, nullptr, qkvb, 1536, 512);

    mha_attn<<<dim3(4, 32), 256, 0, stream>>>(qkvb, ob, x2_attn);

    // x_res[:, 512:] = o @ Wo^T + bo -> bf16 : M=2048 N=512 K=512
    gemm_mfma<false, true><<<dim3(8, 32), 256, 0, stream>>>(
        ob, 512, Wob, 512, bo, nullptr, x_resb + 512, 1024, 512);

    // u = relu(x_res @ W1^T + b1) -> f32 : K=1024
    gemm_mfma<true, false><<<dim3(8, 32), 256, 0, stream>>>(
        x_resb, 1024, W1b, 1024, b1, u_buf, nullptr, 512, 1024);

    // h = LN(x + u) -> f32 h_buf + bf16 hb
    add_ln<<<2048, 256, 0, stream>>>(x, u_buf, g1, be1, h_buf, hb);

    // u = relu(h @ W2^T + b2) -> f32 : K=512
    gemm_mfma<true, false><<<dim3(8, 32), 256, 0, stream>>>(
        hb, 512, W2b, 512, b2, u_buf, nullptr, 512, 512);

    // out = LN(h + u)
    add_ln<<<2048, 256, 0, stream>>>(h_buf, u_buf, g2, be2, out_main, nullptr);

    // P = x @ [d1W1;d2W1]^T -> f32 : M=2048 N=256 K=512
    gemm_mfma<false, false><<<dim3(4, 32), 256, 0, stream>>>(
        xb, 512, Wpb, 512, nullptr, P, nullptr, 256, 512);

    pair_mlp<<<dim3(64, 32), 256, 0, stream>>>(P, x1_attn, x2_attn, d1b1, d1W2,
                                               d1b2, d2b1, d2W2, d2b2, diff1,
                                               diff2);
}

// Round 3
// 212.296 us; speedup vs baseline: 2.6135x; 1.3490x over previous
//
#include <hip/hip_runtime.h>
#include <math.h>

// Problem constants
#define NB 32
#define SS 64
#define EE 512
#define L2T 13.544f
#define LNEPS 1e-5f

using bf16x8 = __attribute__((ext_vector_type(8))) __bf16;
using u16x8  = __attribute__((ext_vector_type(8))) unsigned short;
using f32x4  = __attribute__((ext_vector_type(4))) float;

typedef const void __attribute__((address_space(1))) cv_global;
typedef void __attribute__((address_space(3))) v_lds;

__device__ inline unsigned short f2bf(float f) {
    union { float f; unsigned u; } v; v.f = f;
    unsigned r = v.u + 0x7fff + ((v.u >> 16) & 1);
    return (unsigned short)(r >> 16);
}
__device__ inline float bf2f(unsigned short h) {
    union { unsigned u; float f; } v; v.u = (unsigned)h << 16;
    return v.f;
}

// ---------------------------------------------------------------------------
// Convert x + all weights to bf16 into one contiguous region.
// ---------------------------------------------------------------------------
__global__ __launch_bounds__(256)
void convert_all(const float* __restrict__ x, const float* __restrict__ Wqkv,
                 const float* __restrict__ Wo, const float* __restrict__ W1,
                 const float* __restrict__ W2, const float* __restrict__ d1,
                 const float* __restrict__ d2, unsigned short* __restrict__ dst) {
    int i = blockIdx.x * 256 + threadIdx.x;
    const float* s; int off;
    if (i < 1048576)      { s = x;    off = 0; }
    else if (i < 1835008) { s = Wqkv; off = 1048576; }
    else if (i < 2097152) { s = Wo;   off = 1835008; }
    else if (i < 2621440) { s = W1;   off = 2097152; }
    else if (i < 2883584) { s = W2;   off = 2621440; }
    else if (i < 2949120) { s = d1;   off = 2883584; }
    else                  { s = d2;   off = 2949120; }
    dst[i] = f2bf(s[i - off]);
}

// ---------------------------------------------------------------------------
// Kernel 1: L2-distance attention (fp32 — precision critical) + x1 -> bf16.
// ---------------------------------------------------------------------------
__global__ __launch_bounds__(256)
void l2attn_x1(const float* __restrict__ x, float* __restrict__ x1_attn,
               unsigned short* __restrict__ x_resb) {
    const int f = blockIdx.x, b = blockIdx.y;
    const int tid = threadIdx.x, wave = tid >> 6, lane = tid & 63;
    __shared__ float d2s[64];
    __shared__ float attn_s[64];

    const float4* xb = (const float4*)(x + (size_t)b * SS * EE);
    float4 xf0 = xb[f * 128 + lane * 2];
    float4 xf1 = xb[f * 128 + lane * 2 + 1];

    for (int g = wave; g < 64; g += 4) {
        float4 a0 = xb[g * 128 + lane * 2];
        float4 a1 = xb[g * 128 + lane * 2 + 1];
        float dx, s = 0.f;
        dx = a0.x - xf0.x; s += dx * dx;
        dx = a0.y - xf0.y; s += dx * dx;
        dx = a0.z - xf0.z; s += dx * dx;
        dx = a0.w - xf0.w; s += dx * dx;
        dx = a1.x - xf1.x; s += dx * dx;
        dx = a1.y - xf1.y; s += dx * dx;
        dx = a1.z - xf1.z; s += dx * dx;
        dx = a1.w - xf1.w; s += dx * dx;
        #pragma unroll
        for (int m = 32; m; m >>= 1) s += __shfl_xor(s, m);
        if (lane == 0) d2s[g] = s;
    }
    __syncthreads();

    if (tid < 64) {
        float v = -d2s[tid] * (1.0f / L2T);
        float mx = v;
        #pragma unroll
        for (int m = 32; m; m >>= 1) mx = fmaxf(mx, __shfl_xor(mx, m));
        float e = expf(v - mx);
        float sum = e;
        #pragma unroll
        for (int m = 32; m; m >>= 1) sum += __shfl_xor(sum, m);
        float a = e / sum;
        x1_attn[((size_t)b * SS + f) * SS + tid] = a;
        attn_s[tid] = a;
    }
    __syncthreads();

    const float* xbf = x + (size_t)b * SS * EE;
    float acc0 = 0.f, acc1 = 0.f;
    #pragma unroll 8
    for (int g = 0; g < 64; ++g) {
        float ag = attn_s[g];
        acc0 += ag * xbf[g * EE + tid];
        acc1 += ag * xbf[g * EE + tid + 256];
    }
    unsigned short* dst = x_resb + ((size_t)b * SS + f) * 1024;
    dst[tid] = f2bf(acc0);
    dst[tid + 256] = f2bf(acc1);
}

// ---------------------------------------------------------------------------
// bf16 MFMA GEMM: C[M,N] = A[M,K] @ B[N,K]^T (+bias)(+relu), out fp32 or bf16.
// ---------------------------------------------------------------------------
template <bool RELU, bool OUTBF16>
__global__ __launch_bounds__(256)
void gemm_mfma(const unsigned short* __restrict__ A, int lda,
               const unsigned short* __restrict__ B, int ldb,
               const float* __restrict__ bias, float* __restrict__ Cf,
               unsigned short* __restrict__ Cb, int ldc, int K) {
    __shared__ unsigned short Asl[64 * 32];
    __shared__ unsigned short Bsl[64 * 32];
    const int tid = threadIdx.x;
    const int wave = tid >> 6, lane = tid & 63;
    const int m0 = blockIdx.y * 64, n0 = blockIdx.x * 64;
    const int wm = (wave >> 1) * 32, wn = (wave & 1) * 32;

    f32x4 acc00 = {0.f, 0.f, 0.f, 0.f};
    f32x4 acc01 = acc00, acc10 = acc00, acc11 = acc00;

    const int srow = tid >> 2, scol = (tid & 3) * 8;
    const unsigned short* Ag = A + (size_t)(m0 + srow) * lda + scol;
    const unsigned short* Bg = B + (size_t)(n0 + srow) * ldb + scol;
    v_lds* AslW = (v_lds*)(Asl + wave * 512);
    v_lds* BslW = (v_lds*)(Bsl + wave * 512);

    const int fr = lane & 15;
    const int kq = (lane >> 4) * 8;

    for (int k0 = 0; k0 < K; k0 += 32) {
        __builtin_amdgcn_global_load_lds((cv_global*)(Ag + k0), AslW, 16, 0, 0);
        __builtin_amdgcn_global_load_lds((cv_global*)(Bg + k0), BslW, 16, 0, 0);
        __syncthreads();
        bf16x8 a0 = *(const bf16x8*)(Asl + (wm + fr) * 32 + kq);
        bf16x8 a1 = *(const bf16x8*)(Asl + (wm + 16 + fr) * 32 + kq);
        bf16x8 b0 = *(const bf16x8*)(Bsl + (wn + fr) * 32 + kq);
        bf16x8 b1 = *(const bf16x8*)(Bsl + (wn + 16 + fr) * 32 + kq);
        acc00 = __builtin_amdgcn_mfma_f32_16x16x32_bf16(a0, b0, acc00, 0, 0, 0);
        acc01 = __builtin_amdgcn_mfma_f32_16x16x32_bf16(a0, b1, acc01, 0, 0, 0);
        acc10 = __builtin_amdgcn_mfma_f32_16x16x32_bf16(a1, b0, acc10, 0, 0, 0);
        acc11 = __builtin_amdgcn_mfma_f32_16x16x32_bf16(a1, b1, acc11, 0, 0, 0);
        __syncthreads();
    }

    const int crow = (lane >> 4) * 4, ccol = lane & 15;
    float bj0 = bias ? bias[n0 + wn + ccol] : 0.f;
    float bj1 = bias ? bias[n0 + wn + 16 + ccol] : 0.f;

    auto store_tile = [&](f32x4 acc, int mt, int nt, float bj) {
        #pragma unroll
        for (int r = 0; r < 4; ++r) {
            size_t m = (size_t)(m0 + mt + crow + r);
            int n = n0 + nt + ccol;
            float v = acc[r] + bj;
            if (RELU) v = fmaxf(v, 0.f);
            if (OUTBF16) Cb[m * ldc + n] = f2bf(v);
            else         Cf[m * ldc + n] = v;
        }
    };
    store_tile(acc00, wm,      wn,      bj0);
    store_tile(acc01, wm,      wn + 16, bj1);
    store_tile(acc10, wm + 16, wn,      bj0);
    store_tile(acc11, wm + 16, wn + 16, bj1);
}

// ---------------------------------------------------------------------------
// Kernel 3: MFMA attention. One block per (b, h, half): grid (8, 32).
// Block computes 32 Q-rows x full K/V for one head. Scores fp32 softmax,
// probs bf16 -> PV MFMA. x2_attn head-mean via atomics (fp32 probs).
// ---------------------------------------------------------------------------
__global__ __launch_bounds__(256)
void mha_attn(const unsigned short* __restrict__ qkv,
              unsigned short* __restrict__ o_buf, float* __restrict__ x2_attn) {
    const int hh = blockIdx.x;                 // h*2 + half
    const int h = hh >> 1, half = hh & 1;
    const int b = blockIdx.y;
    const int tid = threadIdx.x, wave = tid >> 6, lane = tid & 63;

    __shared__ unsigned short Qs[32 * 136];    // ld 136: 2-way bank alias, free
    __shared__ unsigned short Ks[64 * 136];
    __shared__ unsigned short Vt[128 * 72];    // transposed V: Vt[d][g]
    __shared__ float sc[32 * 68];
    __shared__ unsigned short Pb[32 * 72];     // probs bf16, A-operand layout

    const unsigned short* base = qkv + (size_t)b * 64 * 1536;

    // stage Q (32x128): thread -> row tid>>3, col (tid&7)*16
    {
        int row = tid >> 3, col = (tid & 7) * 16;
        const unsigned short* src = base + (half * 32 + row) * 1536 + h * 128 + col;
        *(u16x8*)(Qs + row * 136 + col)     = *(const u16x8*)(src);
        *(u16x8*)(Qs + row * 136 + col + 8) = *(const u16x8*)(src + 8);
    }
    // stage K (64x128)
    {
        int row = tid >> 2, col = (tid & 3) * 32;
        const unsigned short* src = base + row * 1536 + 512 + h * 128 + col;
        #pragma unroll
        for (int j = 0; j < 4; ++j)
            *(u16x8*)(Ks + row * 136 + col + j * 8) = *(const u16x8*)(src + j * 8);
    }
    // stage V transposed: Vt[d*72 + g]
    {
        int g = tid >> 2, col = (tid & 3) * 32;
        const unsigned short* src = base + g * 1536 + 1024 + h * 128 + col;
        #pragma unroll
        for (int j = 0; j < 4; ++j) {
            u16x8 v = *(const u16x8*)(src + j * 8);
            #pragma unroll
            for (int e = 0; e < 8; ++e)
                Vt[(col + j * 8 + e) * 72 + g] = v[e];
        }
    }
    __syncthreads();

    const int fr = lane & 15, kq = (lane >> 4) * 8;
    const int crow = (lane >> 4) * 4, ccol = lane & 15;
    const int wm = (wave >> 1) * 16;           // waves 0,1 -> rows 0-15; 2,3 -> 16-31

    // QK^T (32x64) -> sc
    {
        const int wn = (wave & 1) * 32;
        f32x4 s0 = {0.f, 0.f, 0.f, 0.f}, s1 = s0;
        #pragma unroll
        for (int k0 = 0; k0 < 128; k0 += 32) {
            bf16x8 a  = *(const bf16x8*)(Qs + (wm + fr) * 136 + k0 + kq);
            bf16x8 b0 = *(const bf16x8*)(Ks + (wn + fr) * 136 + k0 + kq);
            bf16x8 b1 = *(const bf16x8*)(Ks + (wn + 16 + fr) * 136 + k0 + kq);
            s0 = __builtin_amdgcn_mfma_f32_16x16x32_bf16(a, b0, s0, 0, 0, 0);
            s1 = __builtin_amdgcn_mfma_f32_16x16x32_bf16(a, b1, s1, 0, 0, 0);
        }
        const float scale = 0.08838834764831845f;  // 1/sqrt(128)
        #pragma unroll
        for (int r = 0; r < 4; ++r) {
            sc[(wm + crow + r) * 68 + wn + ccol]      = s0[r] * scale;
            sc[(wm + crow + r) * 68 + wn + 16 + ccol] = s1[r] * scale;
        }
    }
    __syncthreads();

    // softmax: 8 rows per wave, lane = col
    #pragma unroll
    for (int i = 0; i < 8; ++i) {
        int f = wave * 8 + i;
        float v = sc[f * 68 + lane];
        float mx = v;
        #pragma unroll
        for (int m = 32; m; m >>= 1) mx = fmaxf(mx, __shfl_xor(mx, m));
        float e = expf(v - mx);
        float sum = e;
        #pragma unroll
        for (int m = 32; m; m >>= 1) sum += __shfl_xor(sum, m);
        float a = e / sum;
        Pb[f * 72 + lane] = f2bf(a);
        atomicAdd(&x2_attn[((size_t)b * 64 + half * 32 + f) * 64 + lane], 0.25f * a);
    }
    __syncthreads();

    // PV: per wave 16 rows x 64 cols
    {
        const int wn2 = (wave & 1) * 64;
        f32x4 o[4];
        #pragma unroll
        for (int t = 0; t < 4; ++t) o[t] = f32x4{0.f, 0.f, 0.f, 0.f};
        #pragma unroll
        for (int k0 = 0; k0 < 64; k0 += 32) {
            bf16x8 a = *(const bf16x8*)(Pb + (wm + fr) * 72 + k0 + kq);
            #pragma unroll
            for (int t = 0; t < 4; ++t) {
                bf16x8 bv = *(const bf16x8*)(Vt + (wn2 + t * 16 + fr) * 72 + k0 + kq);
                o[t] = __builtin_amdgcn_mfma_f32_16x16x32_bf16(a, bv, o[t], 0, 0, 0);
            }
        }
        #pragma unroll
        for (int t = 0; t < 4; ++t) {
            #pragma unroll
            for (int r = 0; r < 4; ++r) {
                size_t m = (size_t)b * 64 + half * 32 + wm + crow + r;
                int col = h * 128 + wn2 + t * 16 + ccol;
                o_buf[m * 512 + col] = f2bf(o[t][r]);
            }
        }
    }
}

// ---------------------------------------------------------------------------
// Kernel 4: out = LayerNorm(base + u) * g + be (+ optional bf16 copy).
// ---------------------------------------------------------------------------
__global__ __launch_bounds__(256)
void add_ln(const float* __restrict__ base, const float* __restrict__ u,
            const float* __restrict__ gam, const float* __restrict__ bet,
            float* __restrict__ out, unsigned short* __restrict__ outb) {
    const int row = blockIdx.x;
    const int tid = threadIdx.x, wave = tid >> 6, lane = tid & 63;
    const float* br = base + (size_t)row * EE;
    const float* ur = u + (size_t)row * EE;
    float t0 = br[tid] + ur[tid];
    float t1 = br[tid + 256] + ur[tid + 256];
    float s = t0 + t1, sq = t0 * t0 + t1 * t1;
    #pragma unroll
    for (int m = 32; m; m >>= 1) {
        s += __shfl_xor(s, m);
        sq += __shfl_xor(sq, m);
    }
    __shared__ float ssum[4], ssq[4];
    if (lane == 0) { ssum[wave] = s; ssq[wave] = sq; }
    __syncthreads();
    s = ssum[0] + ssum[1] + ssum[2] + ssum[3];
    sq = ssq[0] + ssq[1] + ssq[2] + ssq[3];
    float mean = s * (1.0f / EE);
    float var = sq * (1.0f / EE) - mean * mean;
    float inv = rsqrtf(var + LNEPS);
    float v0 = (t0 - mean) * inv * gam[tid] + bet[tid];
    float v1 = (t1 - mean) * inv * gam[tid + 256] + bet[tid + 256];
    float* orow = out + (size_t)row * EE;
    orow[tid] = v0;
    orow[tid + 256] = v1;
    if (outb) {
        unsigned short* obr = outb + (size_t)row * EE;
        obr[tid] = f2bf(v0);
        obr[tid + 256] = f2bf(v1);
    }
}

// ---------------------------------------------------------------------------
// Kernel 5: pair MLPs via projection trick. P[row][0:128]=P1, [128:256]=P2.
// ---------------------------------------------------------------------------
__global__ __launch_bounds__(256)
void pair_mlp(const float* __restrict__ P, const float* __restrict__ a1,
              const float* __restrict__ a2, const float* __restrict__ d1b1,
              const float* __restrict__ d1w2, const float* __restrict__ d1b2,
              const float* __restrict__ d2b1, const float* __restrict__ d2w2,
              const float* __restrict__ d2b2, float* __restrict__ out1,
              float* __restrict__ out2) {
    const int f = blockIdx.x, b = blockIdx.y;
    const int tid = threadIdx.x, wave = tid >> 6, lane = tid & 63;
    const size_t row = (size_t)b * SS + f;
    const int c0 = lane * 2, c1 = lane * 2 + 1;

    const float p1f0 = P[row * 256 + c0],       p1f1 = P[row * 256 + c1];
    const float p2f0 = P[row * 256 + 128 + c0], p2f1 = P[row * 256 + 128 + c1];
    const float w10 = d1w2[c0], w11 = d1w2[c1];
    const float w20 = d2w2[c0], w21 = d2w2[c1];
    const float b10 = d1b1[c0], b11 = d1b1[c1];
    const float b20 = d2b1[c0], b21 = d2b1[c1];
    const float bb1 = d1b2[0], bb2 = d2b2[0];

    const float* a1r = a1 + row * SS;
    const float* a2r = a2 + row * SS;
    const size_t bbase = (size_t)b * SS * 256;

    for (int g = wave; g < 64; g += 4) {
        float aa1 = a1r[g], aa2 = a2r[g];
        float q10 = P[bbase + g * 256 + c0],       q11 = P[bbase + g * 256 + c1];
        float q20 = P[bbase + g * 256 + 128 + c0], q21 = P[bbase + g * 256 + 128 + c1];
        float h10 = fmaxf(aa1 * (q10 - p1f0) + b10, 0.f);
        float h11 = fmaxf(aa1 * (q11 - p1f1) + b11, 0.f);
        float h20 = fmaxf(aa2 * (q20 - p2f0) + b20, 0.f);
        float h21 = fmaxf(aa2 * (q21 - p2f1) + b21, 0.f);
        float s1 = w10 * h10 + w11 * h11;
        float s2 = w20 * h20 + w21 * h21;
        #pragma unroll
        for (int m = 32; m; m >>= 1) {
            s1 += __shfl_xor(s1, m);
            s2 += __shfl_xor(s2, m);
        }
        if (lane == 0) {
            out1[row * SS + g] = fmaxf(s1 + bb1, 0.f);
            out2[row * SS + g] = fmaxf(s2 + bb2, 0.f);
        }
    }
}

// ---------------------------------------------------------------------------
extern "C" void kernel_launch(void* const* d_in, const int* in_sizes, int n_in,
                              void* d_out, int out_size, void* d_ws,
                              size_t ws_size, hipStream_t stream) {
    const float* x    = (const float*)d_in[0];
    const float* Wqkv = (const float*)d_in[1];
    const float* bqkv = (const float*)d_in[2];
    const float* Wo   = (const float*)d_in[3];
    const float* bo   = (const float*)d_in[4];
    const float* W1   = (const float*)d_in[5];
    const float* b1   = (const float*)d_in[6];
    const float* W2   = (const float*)d_in[7];
    const float* b2   = (const float*)d_in[8];
    const float* g1   = (const float*)d_in[9];
    const float* be1  = (const float*)d_in[10];
    const float* g2   = (const float*)d_in[11];
    const float* be2  = (const float*)d_in[12];
    const float* d1W1 = (const float*)d_in[13];
    const float* d1b1 = (const float*)d_in[14];
    const float* d1W2 = (const float*)d_in[15];
    const float* d1b2 = (const float*)d_in[16];
    const float* d2W1 = (const float*)d_in[17];
    const float* d2b1 = (const float*)d_in[18];
    const float* d2W2 = (const float*)d_in[19];
    const float* d2b2 = (const float*)d_in[20];

    float* out      = (float*)d_out;
    float* out_main = out;                         // 32*64*512
    float* x1_attn  = out + 1048576;               // 32*64*64
    float* x2_attn  = out + 1048576 + 131072;
    float* diff1    = out + 1048576 + 2 * 131072;
    float* diff2    = out + 1048576 + 3 * 131072;

    // fp32 workspace
    float* ws    = (float*)d_ws;
    float* u_buf = ws;                  // 2048*512
    float* h_buf = u_buf + 1048576;     // 2048*512
    float* P     = h_buf + 1048576;     // 2048*256
    // bf16 workspace
    unsigned short* bb    = (unsigned short*)(P + 524288);
    unsigned short* xb    = bb;                   // 2048*512
    unsigned short* Wqkvb = bb + 1048576;         // 1536*512
    unsigned short* Wob   = bb + 1835008;         // 512*512
    unsigned short* W1b   = bb + 2097152;         // 512*1024
    unsigned short* W2b   = bb + 2621440;         // 512*512
    unsigned short* Wpb   = bb + 2883584;         // 256*512 (d1W1 ++ d2W1)
    unsigned short* qkvb  = bb + 3014656;         // 2048*1536
    unsigned short* ob    = bb + 6160384;         // 2048*512
    unsigned short* x_resb= bb + 7208960;         // 2048*1024
    unsigned short* hb    = bb + 9306112;         // 2048*512

    hipMemsetAsync(x2_attn, 0, 131072 * sizeof(float), stream);

    convert_all<<<11776, 256, 0, stream>>>(x, Wqkv, Wo, W1, W2, d1W1, d2W1, bb);

    // L2 attention + x1 -> x1_attn (f32 out) and x_resb[:, :512] (bf16)
    l2attn_x1<<<dim3(64, 32), 256, 0, stream>>>(x, x1_attn, x_resb);

    // qkv = x @ Wqkv^T + bqkv -> bf16 : M=2048 N=1536 K=512
    gemm_mfma<false, true><<<dim3(24, 32), 256, 0, stream>>>(
        xb, 512, Wqkvb, 512, bqkv, nullptr, qkvb, 1536, 512);

    // MFMA attention: grid (h*2+half, b)
    mha_attn<<<dim3(8, 32), 256, 0, stream>>>(qkvb, ob, x2_attn);

    // x_res[:, 512:] = o @ Wo^T + bo -> bf16 : M=2048 N=512 K=512
    gemm_mfma<false, true><<<dim3(8, 32), 256, 0, stream>>>(
        ob, 512, Wob, 512, bo, nullptr, x_resb + 512, 1024, 512);

    // u = relu(x_res @ W1^T + b1) -> f32 : K=1024
    gemm_mfma<true, false><<<dim3(8, 32), 256, 0, stream>>>(
        x_resb, 1024, W1b, 1024, b1, u_buf, nullptr, 512, 1024);

    // h = LN(x + u) -> f32 h_buf + bf16 hb
    add_ln<<<2048, 256, 0, stream>>>(x, u_buf, g1, be1, h_buf, hb);

    // u = relu(h @ W2^T + b2) -> f32 : K=512
    gemm_mfma<true, false><<<dim3(8, 32), 256, 0, stream>>>(
        hb, 512, W2b, 512, b2, u_buf, nullptr, 512, 512);

    // out = LN(h + u)
    add_ln<<<2048, 256, 0, stream>>>(h_buf, u_buf, g2, be2, out_main, nullptr);

    // P = x @ [d1W1;d2W1]^T -> f32 : M=2048 N=256 K=512
    gemm_mfma<false, false><<<dim3(4, 32), 256, 0, stream>>>(
        xb, 512, Wpb, 512, nullptr, P, nullptr, 256, 512);

    pair_mlp<<<dim3(64, 32), 256, 0, stream>>>(P, x1_attn, x2_attn, d1b1, d1W2,
                                               d1b2, d2b1, d2W2, d2b2, diff1,
                                               diff2);
}

// Round 4
// 198.060 us; speedup vs baseline: 2.8014x; 1.0719x over previous
//
#include <hip/hip_runtime.h>
#include <math.h>

// Problem constants
#define NB 32
#define SS 64
#define EE 512
#define L2T 13.544f
#define LNEPS 1e-5f

using bf16x8 = __attribute__((ext_vector_type(8))) __bf16;
using u16x8  = __attribute__((ext_vector_type(8))) unsigned short;
using f32x4  = __attribute__((ext_vector_type(4))) float;

typedef const void __attribute__((address_space(1))) cv_global;
typedef void __attribute__((address_space(3))) v_lds;

__device__ inline unsigned short f2bf(float f) {
    union { float f; unsigned u; } v; v.f = f;
    unsigned r = v.u + 0x7fff + ((v.u >> 16) & 1);
    return (unsigned short)(r >> 16);
}
__device__ inline float bf2f(unsigned short h) {
    union { unsigned u; float f; } v; v.u = (unsigned)h << 16;
    return v.f;
}

// ---------------------------------------------------------------------------
// Convert weights to bf16 (float4-vectorized). dst = bb + 1048576.
// Regions in float4 units: Wqkv 196608, Wo 65536, W1 131072, W2 65536,
// d1 16384, d2 16384. Total 491520 float4 = 1920 blocks x 256.
// ---------------------------------------------------------------------------
__global__ __launch_bounds__(256)
void convert_w(const float* __restrict__ Wqkv, const float* __restrict__ Wo,
               const float* __restrict__ W1, const float* __restrict__ W2,
               const float* __restrict__ d1, const float* __restrict__ d2,
               unsigned short* __restrict__ dst) {
    int i = blockIdx.x * 256 + threadIdx.x;
    const float* s; int off;
    if (i < 196608)      { s = Wqkv; off = 0; }
    else if (i < 262144) { s = Wo;   off = 196608; }
    else if (i < 393216) { s = W1;   off = 262144; }
    else if (i < 458752) { s = W2;   off = 393216; }
    else if (i < 475136) { s = d1;   off = 458752; }
    else                 { s = d2;   off = 475136; }
    float4 v = ((const float4*)s)[i - off];
    ushort4 o;
    o.x = f2bf(v.x); o.y = f2bf(v.y); o.z = f2bf(v.z); o.w = f2bf(v.w);
    ((ushort4*)dst)[i] = o;
}

// ---------------------------------------------------------------------------
// Kernel 1: L2-distance attention (fp32 — precision critical) + x1 -> bf16
// into x_resb[:, :512]; also emits xb = bf16(x). One block per (b,f).
// ---------------------------------------------------------------------------
__global__ __launch_bounds__(256)
void l2attn_x1(const float* __restrict__ x, float* __restrict__ x1_attn,
               unsigned short* __restrict__ x_resb,
               unsigned short* __restrict__ xb) {
    const int f = blockIdx.x, b = blockIdx.y;
    const int tid = threadIdx.x, wave = tid >> 6, lane = tid & 63;
    __shared__ float d2s[64];
    __shared__ float attn_s[64];

    const float4* xv = (const float4*)(x + (size_t)b * SS * EE);
    float4 xf0 = xv[f * 128 + lane * 2];
    float4 xf1 = xv[f * 128 + lane * 2 + 1];

    for (int g = wave; g < 64; g += 4) {
        float4 a0 = xv[g * 128 + lane * 2];
        float4 a1 = xv[g * 128 + lane * 2 + 1];
        float dx, s = 0.f;
        dx = a0.x - xf0.x; s += dx * dx;
        dx = a0.y - xf0.y; s += dx * dx;
        dx = a0.z - xf0.z; s += dx * dx;
        dx = a0.w - xf0.w; s += dx * dx;
        dx = a1.x - xf1.x; s += dx * dx;
        dx = a1.y - xf1.y; s += dx * dx;
        dx = a1.z - xf1.z; s += dx * dx;
        dx = a1.w - xf1.w; s += dx * dx;
        #pragma unroll
        for (int m = 32; m; m >>= 1) s += __shfl_xor(s, m);
        if (lane == 0) d2s[g] = s;
    }
    __syncthreads();

    if (tid < 64) {
        float v = -d2s[tid] * (1.0f / L2T);
        float mx = v;
        #pragma unroll
        for (int m = 32; m; m >>= 1) mx = fmaxf(mx, __shfl_xor(mx, m));
        float e = expf(v - mx);
        float sum = e;
        #pragma unroll
        for (int m = 32; m; m >>= 1) sum += __shfl_xor(sum, m);
        float a = e / sum;
        x1_attn[((size_t)b * SS + f) * SS + tid] = a;
        attn_s[tid] = a;
    }
    __syncthreads();

    const float* xbf = x + (size_t)b * SS * EE;
    float acc0 = 0.f, acc1 = 0.f;
    #pragma unroll 8
    for (int g = 0; g < 64; ++g) {
        float ag = attn_s[g];
        acc0 += ag * xbf[g * EE + tid];
        acc1 += ag * xbf[g * EE + tid + 256];
    }
    unsigned short* dst = x_resb + ((size_t)b * SS + f) * 1024;
    dst[tid] = f2bf(acc0);
    dst[tid + 256] = f2bf(acc1);
    // bf16 copy of this row of x (row f of batch b)
    unsigned short* xrow = xb + ((size_t)b * SS + f) * EE;
    xrow[tid] = f2bf(xbf[f * EE + tid]);
    xrow[tid + 256] = f2bf(xbf[f * EE + tid + 256]);
}

// ---------------------------------------------------------------------------
// bf16 MFMA GEMM: C[M,N] = A[M,K] @ B[N,K]^T (+bias)(+relu), out fp32 or bf16.
// BN=64, BK=64, 256 threads. BM=64: wave = 32x32 quadrant (2x2 MFMA frags);
// BM=32: wave = 16x32 (1x2 frags, doubled grid for occupancy).
// LDS layout XOR-swizzled at 16B-chunk granularity on the SOURCE side:
// LDS chunk (r, q) holds global colchunk q^(r&7)  -> conflict-free staging
// AND conflict-free ds_read_b128 fragment reads (global_load_lds forbids
// padding: dest = wave-uniform base + lane*16).
// ---------------------------------------------------------------------------
template <int BM, bool RELU, bool OUTBF16>
__global__ __launch_bounds__(256)
void gemm_mfma(const unsigned short* __restrict__ A, int lda,
               const unsigned short* __restrict__ B, int ldb,
               const float* __restrict__ bias, float* __restrict__ Cf,
               unsigned short* __restrict__ Cb, int ldc, int K) {
    __shared__ unsigned short Asl[BM * 64];
    __shared__ unsigned short Bsl[64 * 64];
    const int tid = threadIdx.x, wave = tid >> 6, lane = tid & 63;
    const int m0 = blockIdx.y * BM, n0 = blockIdx.x * 64;

    constexpr int RF = BM / 32;            // row fragments per wave
    const int wm = (wave >> 1) * (BM / 2);
    const int wn = (wave & 1) * 32;
    const int fr = lane & 15;
    const int kq4 = lane >> 4;             // logical k-chunk base (0..3)

    f32x4 acc[RF][2] = {};

    for (int k0 = 0; k0 < K; k0 += 64) {
        // stage A (BM x 64): BM*8 16B-chunks
        #pragma unroll
        for (int c0 = 0; c0 < BM * 8; c0 += 256) {
            int cc = c0 + tid, r = cc >> 3, q = cc & 7;
            int col = (q ^ (r & 7)) * 8;
            __builtin_amdgcn_global_load_lds(
                (cv_global*)(A + (size_t)(m0 + r) * lda + k0 + col),
                (v_lds*)(Asl + c0 * 8 + wave * 512), 16, 0, 0);
        }
        // stage B (64 x 64): 512 chunks
        #pragma unroll
        for (int c0 = 0; c0 < 512; c0 += 256) {
            int cc = c0 + tid, r = cc >> 3, q = cc & 7;
            int col = (q ^ (r & 7)) * 8;
            __builtin_amdgcn_global_load_lds(
                (cv_global*)(B + (size_t)(n0 + r) * ldb + k0 + col),
                (v_lds*)(Bsl + c0 * 8 + wave * 512), 16, 0, 0);
        }
        __syncthreads();
        #pragma unroll
        for (int j = 0; j < 2; ++j) {
            int kc = kq4 + j * 4;
            int rb0 = wn + fr, rb1 = wn + 16 + fr;
            bf16x8 b0 = *(const bf16x8*)(Bsl + rb0 * 64 + (kc ^ (rb0 & 7)) * 8);
            bf16x8 b1 = *(const bf16x8*)(Bsl + rb1 * 64 + (kc ^ (rb1 & 7)) * 8);
            #pragma unroll
            for (int r = 0; r < RF; ++r) {
                int ra = wm + r * 16 + fr;
                bf16x8 af = *(const bf16x8*)(Asl + ra * 64 + (kc ^ (ra & 7)) * 8);
                acc[r][0] = __builtin_amdgcn_mfma_f32_16x16x32_bf16(af, b0, acc[r][0], 0, 0, 0);
                acc[r][1] = __builtin_amdgcn_mfma_f32_16x16x32_bf16(af, b1, acc[r][1], 0, 0, 0);
            }
        }
        __syncthreads();
    }

    // C/D layout: col = lane&15, row = (lane>>4)*4 + reg
    const int crow = (lane >> 4) * 4, ccol = lane & 15;
    float bj0 = bias ? bias[n0 + wn + ccol] : 0.f;
    float bj1 = bias ? bias[n0 + wn + 16 + ccol] : 0.f;
    #pragma unroll
    for (int r = 0; r < RF; ++r) {
        #pragma unroll
        for (int c = 0; c < 2; ++c) {
            float bj = c ? bj1 : bj0;
            #pragma unroll
            for (int i = 0; i < 4; ++i) {
                size_t m = (size_t)(m0 + wm + r * 16 + crow + i);
                int n = n0 + wn + c * 16 + ccol;
                float v = acc[r][c][i] + bj;
                if (RELU) v = fmaxf(v, 0.f);
                if (OUTBF16) Cb[m * ldc + n] = f2bf(v);
                else         Cf[m * ldc + n] = v;
            }
        }
    }
}

// ---------------------------------------------------------------------------
// Kernel 3: MFMA attention. One block per (b, h, half): grid (8, 32).
// Scores fp32 softmax -> probs f32 to pws (per-head) + bf16 to PV MFMA.
// ---------------------------------------------------------------------------
__global__ __launch_bounds__(256)
void mha_attn(const unsigned short* __restrict__ qkv,
              unsigned short* __restrict__ o_buf, float* __restrict__ pws) {
    const int hh = blockIdx.x;                 // h*2 + half
    const int h = hh >> 1, half = hh & 1;
    const int b = blockIdx.y;
    const int tid = threadIdx.x, wave = tid >> 6, lane = tid & 63;

    __shared__ unsigned short Qs[32 * 136];
    __shared__ unsigned short Ks[64 * 136];
    __shared__ unsigned short Vt[128 * 72];
    __shared__ float sc[32 * 68];
    __shared__ unsigned short Pb[32 * 72];

    const unsigned short* base = qkv + (size_t)b * 64 * 1536;

    {
        int row = tid >> 3, col = (tid & 7) * 16;
        const unsigned short* src = base + (half * 32 + row) * 1536 + h * 128 + col;
        *(u16x8*)(Qs + row * 136 + col)     = *(const u16x8*)(src);
        *(u16x8*)(Qs + row * 136 + col + 8) = *(const u16x8*)(src + 8);
    }
    {
        int row = tid >> 2, col = (tid & 3) * 32;
        const unsigned short* src = base + row * 1536 + 512 + h * 128 + col;
        #pragma unroll
        for (int j = 0; j < 4; ++j)
            *(u16x8*)(Ks + row * 136 + col + j * 8) = *(const u16x8*)(src + j * 8);
    }
    {
        int g = tid >> 2, col = (tid & 3) * 32;
        const unsigned short* src = base + g * 1536 + 1024 + h * 128 + col;
        #pragma unroll
        for (int j = 0; j < 4; ++j) {
            u16x8 v = *(const u16x8*)(src + j * 8);
            #pragma unroll
            for (int e = 0; e < 8; ++e)
                Vt[(col + j * 8 + e) * 72 + g] = v[e];
        }
    }
    __syncthreads();

    const int fr = lane & 15, kq = (lane >> 4) * 8;
    const int crow = (lane >> 4) * 4, ccol = lane & 15;
    const int wm = (wave >> 1) * 16;

    {
        const int wn = (wave & 1) * 32;
        f32x4 s0 = {0.f, 0.f, 0.f, 0.f}, s1 = s0;
        #pragma unroll
        for (int k0 = 0; k0 < 128; k0 += 32) {
            bf16x8 a  = *(const bf16x8*)(Qs + (wm + fr) * 136 + k0 + kq);
            bf16x8 b0 = *(const bf16x8*)(Ks + (wn + fr) * 136 + k0 + kq);
            bf16x8 b1 = *(const bf16x8*)(Ks + (wn + 16 + fr) * 136 + k0 + kq);
            s0 = __builtin_amdgcn_mfma_f32_16x16x32_bf16(a, b0, s0, 0, 0, 0);
            s1 = __builtin_amdgcn_mfma_f32_16x16x32_bf16(a, b1, s1, 0, 0, 0);
        }
        const float scale = 0.08838834764831845f;
        #pragma unroll
        for (int r = 0; r < 4; ++r) {
            sc[(wm + crow + r) * 68 + wn + ccol]      = s0[r] * scale;
            sc[(wm + crow + r) * 68 + wn + 16 + ccol] = s1[r] * scale;
        }
    }
    __syncthreads();

    #pragma unroll
    for (int i = 0; i < 8; ++i) {
        int f = wave * 8 + i;
        float v = sc[f * 68 + lane];
        float mx = v;
        #pragma unroll
        for (int m = 32; m; m >>= 1) mx = fmaxf(mx, __shfl_xor(mx, m));
        float e = expf(v - mx);
        float sum = e;
        #pragma unroll
        for (int m = 32; m; m >>= 1) sum += __shfl_xor(sum, m);
        float a = e / sum;
        Pb[f * 72 + lane] = f2bf(a);
        pws[(((size_t)b * 4 + h) * 64 + half * 32 + f) * 64 + lane] = a;
    }
    __syncthreads();

    {
        const int wn2 = (wave & 1) * 64;
        f32x4 o[4];
        #pragma unroll
        for (int t = 0; t < 4; ++t) o[t] = f32x4{0.f, 0.f, 0.f, 0.f};
        #pragma unroll
        for (int k0 = 0; k0 < 64; k0 += 32) {
            bf16x8 a = *(const bf16x8*)(Pb + (wm + fr) * 72 + k0 + kq);
            #pragma unroll
            for (int t = 0; t < 4; ++t) {
                bf16x8 bv = *(const bf16x8*)(Vt + (wn2 + t * 16 + fr) * 72 + k0 + kq);
                o[t] = __builtin_amdgcn_mfma_f32_16x16x32_bf16(a, bv, o[t], 0, 0, 0);
            }
        }
        #pragma unroll
        for (int t = 0; t < 4; ++t) {
            #pragma unroll
            for (int r = 0; r < 4; ++r) {
                size_t m = (size_t)b * 64 + half * 32 + wm + crow + r;
                int col = h * 128 + wn2 + t * 16 + ccol;
                o_buf[m * 512 + col] = f2bf(o[t][r]);
            }
        }
    }
}

// ---------------------------------------------------------------------------
// Kernel 4: out = LayerNorm(base + u) * g + be (+ optional bf16 copy).
// ---------------------------------------------------------------------------
__global__ __launch_bounds__(256)
void add_ln(const float* __restrict__ base, const float* __restrict__ u,
            const float* __restrict__ gam, const float* __restrict__ bet,
            float* __restrict__ out, unsigned short* __restrict__ outb) {
    const int row = blockIdx.x;
    const int tid = threadIdx.x, wave = tid >> 6, lane = tid & 63;
    const float* br = base + (size_t)row * EE;
    const float* ur = u + (size_t)row * EE;
    float t0 = br[tid] + ur[tid];
    float t1 = br[tid + 256] + ur[tid + 256];
    float s = t0 + t1, sq = t0 * t0 + t1 * t1;
    #pragma unroll
    for (int m = 32; m; m >>= 1) {
        s += __shfl_xor(s, m);
        sq += __shfl_xor(sq, m);
    }
    __shared__ float ssum[4], ssq[4];
    if (lane == 0) { ssum[wave] = s; ssq[wave] = sq; }
    __syncthreads();
    s = ssum[0] + ssum[1] + ssum[2] + ssum[3];
    sq = ssq[0] + ssq[1] + ssq[2] + ssq[3];
    float mean = s * (1.0f / EE);
    float var = sq * (1.0f / EE) - mean * mean;
    float inv = rsqrtf(var + LNEPS);
    float v0 = (t0 - mean) * inv * gam[tid] + bet[tid];
    float v1 = (t1 - mean) * inv * gam[tid + 256] + bet[tid + 256];
    float* orow = out + (size_t)row * EE;
    orow[tid] = v0;
    orow[tid + 256] = v1;
    if (outb) {
        unsigned short* obr = outb + (size_t)row * EE;
        obr[tid] = f2bf(v0);
        obr[tid + 256] = f2bf(v1);
    }
}

// ---------------------------------------------------------------------------
// Kernel 5: pair MLPs via projection trick. Computes x2_attn = head-mean of
// pws inline, writes it, and uses it. P[row][0:128]=P1, [128:256]=P2.
// ---------------------------------------------------------------------------
__global__ __launch_bounds__(256)
void pair_mlp(const float* __restrict__ P, const float* __restrict__ a1,
              const float* __restrict__ pws, const float* __restrict__ d1b1,
              const float* __restrict__ d1w2, const float* __restrict__ d1b2,
              const float* __restrict__ d2b1, const float* __restrict__ d2w2,
              const float* __restrict__ d2b2, float* __restrict__ x2_attn,
              float* __restrict__ out1, float* __restrict__ out2) {
    const int f = blockIdx.x, b = blockIdx.y;
    const int tid = threadIdx.x, wave = tid >> 6, lane = tid & 63;
    const size_t row = (size_t)b * SS + f;
    const int c0 = lane * 2, c1 = lane * 2 + 1;

    const float p1f0 = P[row * 256 + c0],       p1f1 = P[row * 256 + c1];
    const float p2f0 = P[row * 256 + 128 + c0], p2f1 = P[row * 256 + 128 + c1];
    const float w10 = d1w2[c0], w11 = d1w2[c1];
    const float w20 = d2w2[c0], w21 = d2w2[c1];
    const float b10 = d1b1[c0], b11 = d1b1[c1];
    const float b20 = d2b1[c0], b21 = d2b1[c1];
    const float bb1 = d1b2[0], bb2 = d2b2[0];

    const float* a1r = a1 + row * SS;
    const float* ph0 = pws + (((size_t)b * 4 + 0) * 64 + f) * 64;
    const float* ph1 = pws + (((size_t)b * 4 + 1) * 64 + f) * 64;
    const float* ph2 = pws + (((size_t)b * 4 + 2) * 64 + f) * 64;
    const float* ph3 = pws + (((size_t)b * 4 + 3) * 64 + f) * 64;
    const size_t bbase = (size_t)b * SS * 256;

    for (int g = wave; g < 64; g += 4) {
        float aa1 = a1r[g];
        float aa2 = 0.25f * (ph0[g] + ph1[g] + ph2[g] + ph3[g]);
        float q10 = P[bbase + g * 256 + c0],       q11 = P[bbase + g * 256 + c1];
        float q20 = P[bbase + g * 256 + 128 + c0], q21 = P[bbase + g * 256 + 128 + c1];
        float h10 = fmaxf(aa1 * (q10 - p1f0) + b10, 0.f);
        float h11 = fmaxf(aa1 * (q11 - p1f1) + b11, 0.f);
        float h20 = fmaxf(aa2 * (q20 - p2f0) + b20, 0.f);
        float h21 = fmaxf(aa2 * (q21 - p2f1) + b21, 0.f);
        float s1 = w10 * h10 + w11 * h11;
        float s2 = w20 * h20 + w21 * h21;
        #pragma unroll
        for (int m = 32; m; m >>= 1) {
            s1 += __shfl_xor(s1, m);
            s2 += __shfl_xor(s2, m);
        }
        if (lane == 0) {
            x2_attn[row * SS + g] = aa2;
            out1[row * SS + g] = fmaxf(s1 + bb1, 0.f);
            out2[row * SS + g] = fmaxf(s2 + bb2, 0.f);
        }
    }
}

// ---------------------------------------------------------------------------
extern "C" void kernel_launch(void* const* d_in, const int* in_sizes, int n_in,
                              void* d_out, int out_size, void* d_ws,
                              size_t ws_size, hipStream_t stream) {
    const float* x    = (const float*)d_in[0];
    const float* Wqkv = (const float*)d_in[1];
    const float* bqkv = (const float*)d_in[2];
    const float* Wo   = (const float*)d_in[3];
    const float* bo   = (const float*)d_in[4];
    const float* W1   = (const float*)d_in[5];
    const float* b1   = (const float*)d_in[6];
    const float* W2   = (const float*)d_in[7];
    const float* b2   = (const float*)d_in[8];
    const float* g1   = (const float*)d_in[9];
    const float* be1  = (const float*)d_in[10];
    const float* g2   = (const float*)d_in[11];
    const float* be2  = (const float*)d_in[12];
    const float* d1W1 = (const float*)d_in[13];
    const float* d1b1 = (const float*)d_in[14];
    const float* d1W2 = (const float*)d_in[15];
    const float* d1b2 = (const float*)d_in[16];
    const float* d2W1 = (const float*)d_in[17];
    const float* d2b1 = (const float*)d_in[18];
    const float* d2W2 = (const float*)d_in[19];
    const float* d2b2 = (const float*)d_in[20];

    float* out      = (float*)d_out;
    float* out_main = out;                         // 32*64*512
    float* x1_attn  = out + 1048576;               // 32*64*64
    float* x2_attn  = out + 1048576 + 131072;
    float* diff1    = out + 1048576 + 2 * 131072;
    float* diff2    = out + 1048576 + 3 * 131072;

    // fp32 workspace
    float* ws    = (float*)d_ws;
    float* u_buf = ws;                  // 2048*512
    float* h_buf = u_buf + 1048576;     // 2048*512
    float* P     = h_buf + 1048576;     // 2048*256
    float* pws   = P + 524288;          // 32*4*64*64 per-head probs
    // bf16 workspace
    unsigned short* bb    = (unsigned short*)(pws + 524288);
    unsigned short* xb    = bb;                   // 2048*512
    unsigned short* Wqkvb = bb + 1048576;         // 1536*512
    unsigned short* Wob   = bb + 1835008;         // 512*512
    unsigned short* W1b   = bb + 2097152;         // 512*1024
    unsigned short* W2b   = bb + 2621440;         // 512*512
    unsigned short* Wpb   = bb + 2883584;         // 256*512 (d1W1 ++ d2W1)
    unsigned short* qkvb  = bb + 3014656;         // 2048*1536
    unsigned short* ob    = bb + 6160384;         // 2048*512
    unsigned short* x_resb= bb + 7208960;         // 2048*1024
    unsigned short* hb    = bb + 9306112;         // 2048*512

    // weights -> bf16 (float4-vectorized, weights only; xb comes from l2attn)
    convert_w<<<1920, 256, 0, stream>>>(Wqkv, Wo, W1, W2, d1W1, d2W1,
                                        bb + 1048576);

    // L2 attention + x1 -> x1_attn, x_resb[:, :512], xb
    l2attn_x1<<<dim3(64, 32), 256, 0, stream>>>(x, x1_attn, x_resb, xb);

    // qkv = x @ Wqkv^T + bqkv -> bf16 : M=2048 N=1536 K=512
    gemm_mfma<64, false, true><<<dim3(24, 32), 256, 0, stream>>>(
        xb, 512, Wqkvb, 512, bqkv, nullptr, qkvb, 1536, 512);

    // MFMA attention: grid (h*2+half, b); probs -> pws
    mha_attn<<<dim3(8, 32), 256, 0, stream>>>(qkvb, ob, pws);

    // x_res[:, 512:] = o @ Wo^T + bo -> bf16 : M=2048 N=512 K=512
    gemm_mfma<32, false, true><<<dim3(8, 64), 256, 0, stream>>>(
        ob, 512, Wob, 512, bo, nullptr, x_resb + 512, 1024, 512);

    // u = relu(x_res @ W1^T + b1) -> f32 : K=1024
    gemm_mfma<32, true, false><<<dim3(8, 64), 256, 0, stream>>>(
        x_resb, 1024, W1b, 1024, b1, u_buf, nullptr, 512, 1024);

    // h = LN(x + u) -> f32 h_buf + bf16 hb
    add_ln<<<2048, 256, 0, stream>>>(x, u_buf, g1, be1, h_buf, hb);

    // u = relu(h @ W2^T + b2) -> f32 : K=512
    gemm_mfma<32, true, false><<<dim3(8, 64), 256, 0, stream>>>(
        hb, 512, W2b, 512, b2, u_buf, nullptr, 512, 512);

    // out = LN(h + u)
    add_ln<<<2048, 256, 0, stream>>>(h_buf, u_buf, g2, be2, out_main, nullptr);

    // P = x @ [d1W1;d2W1]^T -> f32 : M=2048 N=256 K=512
    gemm_mfma<32, false, false><<<dim3(4, 64), 256, 0, stream>>>(
        xb, 512, Wpb, 512, nullptr, P, nullptr, 256, 512);

    // pair MLPs (+ x2_attn head-mean write)
    pair_mlp<<<dim3(64, 32), 256, 0, stream>>>(P, x1_attn, pws, d1b1, d1W2,
                                               d1b2, d2b1, d2W2, d2b2, x2_attn,
                                               diff1, diff2);
}

// Round 5
// 191.190 us; speedup vs baseline: 2.9020x; 1.0359x over previous
//
#include <hip/hip_runtime.h>
#include <math.h>

// Problem constants
#define SS 64
#define EE 512
#define L2T 13.544f
#define LNEPS 1e-5f

using bf16x8 = __attribute__((ext_vector_type(8))) __bf16;
using u16x8  = __attribute__((ext_vector_type(8))) unsigned short;
using f32x4  = __attribute__((ext_vector_type(4))) float;

typedef const void __attribute__((address_space(1))) cv_global;
typedef void __attribute__((address_space(3))) v_lds;

__device__ inline unsigned short f2bf(float f) {
    union { float f; unsigned u; } v; v.f = f;
    unsigned r = v.u + 0x7fff + ((v.u >> 16) & 1);
    return (unsigned short)(r >> 16);
}
__device__ inline float bf2f(unsigned short h) {
    union { unsigned u; float f; } v; v.u = (unsigned)h << 16;
    return v.f;
}

// ---- workspace layout -------------------------------------------------------
// f32 (float offsets): u_buf@0 (1048576), h_buf@1048576, pws@2097152 (524288),
//                      b_eff@2621440 (512). bb (bf16) starts at f32 2621952.
// bb (ushort offsets):
//   XB     0        (2048x512)   bf16(x)
//   WFULL  1048576  (1792x512)   Wqkv rows 0-1535, d1W1 1536-1663, d2W1 1664-1791
//   W1CB   1966080  (512x1024)   cols 0-511 = W1a, cols 512-1023 = Wc=W1b@Wo
//   W2B    2490368  (512x512)
//   QKVB   2752512  (2048x1536)
//   X1O    5898240  (2048x1024)  cols 0-511 = x1 (l2attn), 512-1023 = o (mha)
//   HB     7995392  (2048x512)
//   PB     9043968  (2048x256)   bf16 P projections
#define XB_O    0
#define WFULL_O 1048576
#define W1CB_O  1966080
#define W2B_O   2490368
#define QKVB_O  2752512
#define X1O_O   5898240
#define HB_O    7995392
#define PB_O    9043968

// ---------------------------------------------------------------------------
// MEGA-1: weight convert (blocks 0-1407) + Wc=W1b@Wo prep GEMM (1408-1471)
// + b_eff = b1 + W1b@bo (1472-1475) + L2-attention/x1 (1476-3523).
// All parts depend only on kernel inputs -> one launch, mutual latency hiding.
// ---------------------------------------------------------------------------
__global__ __launch_bounds__(256)
void mega1(const float* __restrict__ x, const float* __restrict__ Wqkv,
           const float* __restrict__ Wo, const float* __restrict__ W1,
           const float* __restrict__ W2, const float* __restrict__ d1,
           const float* __restrict__ d2, const float* __restrict__ b1,
           const float* __restrict__ bo, unsigned short* __restrict__ bb,
           float* __restrict__ b_eff, float* __restrict__ x1_attn) {
    const int bx = blockIdx.x, tid = threadIdx.x;
    __shared__ unsigned short ps[5120];   // prep: Asl[64*40] ++ Bsl[64*40]
    __shared__ float l2s[128];            // l2attn: d2s[64] ++ attn[64]

    if (bx < 1408) {
        // ---- convert weights to bf16 (float4-vectorized) ----
        int i = bx * 256 + tid;
        ushort4* dst4 = (ushort4*)bb;
        const float4* s; int di;
        if (i < 196608)      { s = (const float4*)Wqkv + i;          di = WFULL_O/4 + i; }
        else if (i < 212992) { int j = i-196608; s = (const float4*)d1 + j; di = WFULL_O/4 + 196608 + j; }
        else if (i < 229376) { int j = i-212992; s = (const float4*)d2 + j; di = WFULL_O/4 + 212992 + j; }
        else if (i < 294912) { int j = i-229376; s = (const float4*)W2 + j; di = W2B_O/4 + j; }
        else                 { int j = i-294912; int r = j>>7, cq = j&127;
                               s = (const float4*)W1 + r*256 + cq;   di = W1CB_O/4 + r*256 + cq; }
        float4 v = *s;
        ushort4 o;
        o.x = f2bf(v.x); o.y = f2bf(v.y); o.z = f2bf(v.z); o.w = f2bf(v.w);
        dst4[di] = o;
    } else if (bx < 1472) {
        // ---- prep: Wc[m,j] = sum_k W1b[m,k] * Wo[k,j], 64x64 tiles ----
        const int tb = bx - 1408;
        const int m0 = (tb >> 3) * 64, n0 = (tb & 7) * 64;
        unsigned short* Asl = ps;            // [64][40] pad ld=40 (16B-aligned)
        unsigned short* Bsl = ps + 64 * 40;  // [64][40] transposed Wo tile
        const int wave = tid >> 6, lane = tid & 63;
        const int wm = (wave >> 1) * 32, wn = (wave & 1) * 32;
        const int fr = lane & 15, kq = (lane >> 4) * 8;
        f32x4 acc[2][2] = {};
        for (int k0 = 0; k0 < 512; k0 += 32) {
            {   // A tile: W1b rows (fp32 -> bf16)
                int m = tid >> 2, kk = (tid & 3) * 8;
                const float* src = W1 + (size_t)(m0 + m) * 1024 + 512 + k0 + kk;
                float4 v0 = *(const float4*)src, v1 = *(const float4*)(src + 4);
                u16x8 t = {f2bf(v0.x), f2bf(v0.y), f2bf(v0.z), f2bf(v0.w),
                           f2bf(v1.x), f2bf(v1.y), f2bf(v1.z), f2bf(v1.w)};
                *(u16x8*)(Asl + m * 40 + kk) = t;
            }
            {   // B tile: Wo[k, n0+j] transposed into Bsl[j][k]
                int k = tid >> 3, jq = (tid & 7) * 8;
                const float* src = Wo + (size_t)(k0 + k) * 512 + n0 + jq;
                float4 v0 = *(const float4*)src, v1 = *(const float4*)(src + 4);
                float vv[8] = {v0.x, v0.y, v0.z, v0.w, v1.x, v1.y, v1.z, v1.w};
                #pragma unroll
                for (int e = 0; e < 8; ++e) Bsl[(jq + e) * 40 + k] = f2bf(vv[e]);
            }
            __syncthreads();
            bf16x8 a0 = *(const bf16x8*)(Asl + (wm + fr) * 40 + kq);
            bf16x8 a1 = *(const bf16x8*)(Asl + (wm + 16 + fr) * 40 + kq);
            bf16x8 b0 = *(const bf16x8*)(Bsl + (wn + fr) * 40 + kq);
            bf16x8 b1 = *(const bf16x8*)(Bsl + (wn + 16 + fr) * 40 + kq);
            acc[0][0] = __builtin_amdgcn_mfma_f32_16x16x32_bf16(a0, b0, acc[0][0], 0, 0, 0);
            acc[0][1] = __builtin_amdgcn_mfma_f32_16x16x32_bf16(a0, b1, acc[0][1], 0, 0, 0);
            acc[1][0] = __builtin_amdgcn_mfma_f32_16x16x32_bf16(a1, b0, acc[1][0], 0, 0, 0);
            acc[1][1] = __builtin_amdgcn_mfma_f32_16x16x32_bf16(a1, b1, acc[1][1], 0, 0, 0);
            __syncthreads();
        }
        unsigned short* W1cb = bb + W1CB_O;
        const int crow = (lane >> 4) * 4, ccol = lane & 15;
        #pragma unroll
        for (int r2 = 0; r2 < 2; ++r2)
            #pragma unroll
            for (int c2 = 0; c2 < 2; ++c2)
                #pragma unroll
                for (int i = 0; i < 4; ++i) {
                    int m = m0 + wm + r2 * 16 + crow + i;
                    int j = n0 + wn + c2 * 16 + ccol;
                    W1cb[(size_t)m * 1024 + 512 + j] = f2bf(acc[r2][c2][i]);
                }
    } else if (bx < 1476) {
        // ---- b_eff[n] = b1[n] + sum_k W1b[n,k]*bo[k] ----
        int n = (bx - 1472) * 128 + (tid >> 1);
        int kh = (tid & 1) * 256;
        float s = 0.f;
        for (int k = 0; k < 256; ++k)
            s += W1[(size_t)n * 1024 + 512 + kh + k] * bo[kh + k];
        s += __shfl_xor(s, 1);
        if ((tid & 1) == 0) b_eff[n] = b1[n] + s;
    } else {
        // ---- L2-distance attention (fp32) + x1 -> bf16, + xb emit ----
        const int idx = bx - 1476;
        const int b = idx >> 6, f = idx & 63;
        const int wave = tid >> 6, lane = tid & 63;
        float* d2s = l2s; float* attn_s = l2s + 64;

        const float4* xv = (const float4*)(x + (size_t)b * SS * EE);
        float4 xf0 = xv[f * 128 + lane * 2];
        float4 xf1 = xv[f * 128 + lane * 2 + 1];

        for (int g = wave; g < 64; g += 4) {
            float4 a0 = xv[g * 128 + lane * 2];
            float4 a1 = xv[g * 128 + lane * 2 + 1];
            float dx, s = 0.f;
            dx = a0.x - xf0.x; s += dx * dx;
            dx = a0.y - xf0.y; s += dx * dx;
            dx = a0.z - xf0.z; s += dx * dx;
            dx = a0.w - xf0.w; s += dx * dx;
            dx = a1.x - xf1.x; s += dx * dx;
            dx = a1.y - xf1.y; s += dx * dx;
            dx = a1.z - xf1.z; s += dx * dx;
            dx = a1.w - xf1.w; s += dx * dx;
            #pragma unroll
            for (int m = 32; m; m >>= 1) s += __shfl_xor(s, m);
            if (lane == 0) d2s[g] = s;
        }
        __syncthreads();
        if (tid < 64) {
            float v = -d2s[tid] * (1.0f / L2T);
            float mx = v;
            #pragma unroll
            for (int m = 32; m; m >>= 1) mx = fmaxf(mx, __shfl_xor(mx, m));
            float e = expf(v - mx);
            float sum = e;
            #pragma unroll
            for (int m = 32; m; m >>= 1) sum += __shfl_xor(sum, m);
            float a = e / sum;
            x1_attn[((size_t)b * SS + f) * SS + tid] = a;
            attn_s[tid] = a;
        }
        __syncthreads();
        const float* xbf = x + (size_t)b * SS * EE;
        float acc0 = 0.f, acc1 = 0.f;
        #pragma unroll 8
        for (int g = 0; g < 64; ++g) {
            float ag = attn_s[g];
            acc0 += ag * xbf[g * EE + tid];
            acc1 += ag * xbf[g * EE + tid + 256];
        }
        unsigned short* dst = bb + X1O_O + ((size_t)b * SS + f) * 1024;
        dst[tid] = f2bf(acc0);
        dst[tid + 256] = f2bf(acc1);
        unsigned short* xrow = bb + XB_O + ((size_t)b * SS + f) * EE;
        xrow[tid] = f2bf(xbf[f * EE + tid]);
        xrow[tid + 256] = f2bf(xbf[f * EE + tid + 256]);
    }
}

// ---------------------------------------------------------------------------
// Fused qkv + P GEMM: C = xb @ Wfull^T.  Wfull = [Wqkv(1536) ; d1W1 ; d2W1].
// bx<24 -> qkvb (ld 1536, +bqkv bias); bx>=24 -> Pb (ld 256, no bias).
// BM=BN=64, BK=64, XOR-swizzled global_load_lds staging.
// ---------------------------------------------------------------------------
__global__ __launch_bounds__(256)
void gemm_qkvp(const unsigned short* __restrict__ A,
               const unsigned short* __restrict__ B,
               const float* __restrict__ bias,
               unsigned short* __restrict__ Cq, unsigned short* __restrict__ Cp) {
    __shared__ unsigned short Asl[64 * 64];
    __shared__ unsigned short Bsl[64 * 64];
    const int tid = threadIdx.x, wave = tid >> 6, lane = tid & 63;
    const int m0 = blockIdx.y * 64, n0 = blockIdx.x * 64;
    const int wm = (wave >> 1) * 32, wn = (wave & 1) * 32;
    const int fr = lane & 15, kq4 = lane >> 4;
    f32x4 acc[2][2] = {};

    for (int k0 = 0; k0 < 512; k0 += 64) {
        #pragma unroll
        for (int c0 = 0; c0 < 512; c0 += 256) {
            int cc = c0 + tid, r = cc >> 3, q = cc & 7;
            int col = (q ^ (r & 7)) * 8;
            __builtin_amdgcn_global_load_lds(
                (cv_global*)(A + (size_t)(m0 + r) * 512 + k0 + col),
                (v_lds*)(Asl + c0 * 8 + wave * 512), 16, 0, 0);
        }
        #pragma unroll
        for (int c0 = 0; c0 < 512; c0 += 256) {
            int cc = c0 + tid, r = cc >> 3, q = cc & 7;
            int col = (q ^ (r & 7)) * 8;
            __builtin_amdgcn_global_load_lds(
                (cv_global*)(B + (size_t)(n0 + r) * 512 + k0 + col),
                (v_lds*)(Bsl + c0 * 8 + wave * 512), 16, 0, 0);
        }
        __syncthreads();
        #pragma unroll
        for (int j = 0; j < 2; ++j) {
            int kc = kq4 + j * 4;
            int rb0 = wn + fr, rb1 = wn + 16 + fr;
            bf16x8 b0 = *(const bf16x8*)(Bsl + rb0 * 64 + (kc ^ (rb0 & 7)) * 8);
            bf16x8 b1 = *(const bf16x8*)(Bsl + rb1 * 64 + (kc ^ (rb1 & 7)) * 8);
            #pragma unroll
            for (int r = 0; r < 2; ++r) {
                int ra = wm + r * 16 + fr;
                bf16x8 af = *(const bf16x8*)(Asl + ra * 64 + (kc ^ (ra & 7)) * 8);
                acc[r][0] = __builtin_amdgcn_mfma_f32_16x16x32_bf16(af, b0, acc[r][0], 0, 0, 0);
                acc[r][1] = __builtin_amdgcn_mfma_f32_16x16x32_bf16(af, b1, acc[r][1], 0, 0, 0);
            }
        }
        __syncthreads();
    }

    const int crow = (lane >> 4) * 4, ccol = lane & 15;
    if (blockIdx.x < 24) {
        float bj0 = bias[n0 + wn + ccol], bj1 = bias[n0 + wn + 16 + ccol];
        #pragma unroll
        for (int r = 0; r < 2; ++r)
            #pragma unroll
            for (int c = 0; c < 2; ++c) {
                float bj = c ? bj1 : bj0;
                #pragma unroll
                for (int i = 0; i < 4; ++i) {
                    size_t m = (size_t)(m0 + wm + r * 16 + crow + i);
                    int n = n0 + wn + c * 16 + ccol;
                    Cq[m * 1536 + n] = f2bf(acc[r][c][i] + bj);
                }
            }
    } else {
        int p0 = n0 - 1536;
        #pragma unroll
        for (int r = 0; r < 2; ++r)
            #pragma unroll
            for (int c = 0; c < 2; ++c)
                #pragma unroll
                for (int i = 0; i < 4; ++i) {
                    size_t m = (size_t)(m0 + wm + r * 16 + crow + i);
                    int n = p0 + wn + c * 16 + ccol;
                    Cp[m * 256 + n] = f2bf(acc[r][c][i]);
                }
    }
}

// ---------------------------------------------------------------------------
// MFMA attention. Block per (b, h, half). o written straight into x1o[:,512:].
// ---------------------------------------------------------------------------
__global__ __launch_bounds__(256)
void mha_attn(const unsigned short* __restrict__ qkv,
              unsigned short* __restrict__ x1o, float* __restrict__ pws) {
    const int hh = blockIdx.x;
    const int h = hh >> 1, half = hh & 1;
    const int b = blockIdx.y;
    const int tid = threadIdx.x, wave = tid >> 6, lane = tid & 63;

    __shared__ unsigned short Qs[32 * 136];
    __shared__ unsigned short Ks[64 * 136];
    __shared__ unsigned short Vt[128 * 72];
    __shared__ float sc[32 * 68];
    __shared__ unsigned short Pbf[32 * 72];

    const unsigned short* base = qkv + (size_t)b * 64 * 1536;
    {
        int row = tid >> 3, col = (tid & 7) * 16;
        const unsigned short* src = base + (half * 32 + row) * 1536 + h * 128 + col;
        *(u16x8*)(Qs + row * 136 + col)     = *(const u16x8*)(src);
        *(u16x8*)(Qs + row * 136 + col + 8) = *(const u16x8*)(src + 8);
    }
    {
        int row = tid >> 2, col = (tid & 3) * 32;
        const unsigned short* src = base + row * 1536 + 512 + h * 128 + col;
        #pragma unroll
        for (int j = 0; j < 4; ++j)
            *(u16x8*)(Ks + row * 136 + col + j * 8) = *(const u16x8*)(src + j * 8);
    }
    {
        int g = tid >> 2, col = (tid & 3) * 32;
        const unsigned short* src = base + g * 1536 + 1024 + h * 128 + col;
        #pragma unroll
        for (int j = 0; j < 4; ++j) {
            u16x8 v = *(const u16x8*)(src + j * 8);
            #pragma unroll
            for (int e = 0; e < 8; ++e)
                Vt[(col + j * 8 + e) * 72 + g] = v[e];
        }
    }
    __syncthreads();

    const int fr = lane & 15, kq = (lane >> 4) * 8;
    const int crow = (lane >> 4) * 4, ccol = lane & 15;
    const int wm = (wave >> 1) * 16;
    {
        const int wn = (wave & 1) * 32;
        f32x4 s0 = {0.f, 0.f, 0.f, 0.f}, s1 = s0;
        #pragma unroll
        for (int k0 = 0; k0 < 128; k0 += 32) {
            bf16x8 a  = *(const bf16x8*)(Qs + (wm + fr) * 136 + k0 + kq);
            bf16x8 b0 = *(const bf16x8*)(Ks + (wn + fr) * 136 + k0 + kq);
            bf16x8 b1 = *(const bf16x8*)(Ks + (wn + 16 + fr) * 136 + k0 + kq);
            s0 = __builtin_amdgcn_mfma_f32_16x16x32_bf16(a, b0, s0, 0, 0, 0);
            s1 = __builtin_amdgcn_mfma_f32_16x16x32_bf16(a, b1, s1, 0, 0, 0);
        }
        const float scale = 0.08838834764831845f;
        #pragma unroll
        for (int r = 0; r < 4; ++r) {
            sc[(wm + crow + r) * 68 + wn + ccol]      = s0[r] * scale;
            sc[(wm + crow + r) * 68 + wn + 16 + ccol] = s1[r] * scale;
        }
    }
    __syncthreads();

    #pragma unroll
    for (int i = 0; i < 8; ++i) {
        int f = wave * 8 + i;
        float v = sc[f * 68 + lane];
        float mx = v;
        #pragma unroll
        for (int m = 32; m; m >>= 1) mx = fmaxf(mx, __shfl_xor(mx, m));
        float e = expf(v - mx);
        float sum = e;
        #pragma unroll
        for (int m = 32; m; m >>= 1) sum += __shfl_xor(sum, m);
        float a = e / sum;
        Pbf[f * 72 + lane] = f2bf(a);
        pws[(((size_t)b * 4 + h) * 64 + half * 32 + f) * 64 + lane] = a;
    }
    __syncthreads();

    {
        const int wn2 = (wave & 1) * 64;
        f32x4 o[4];
        #pragma unroll
        for (int t = 0; t < 4; ++t) o[t] = f32x4{0.f, 0.f, 0.f, 0.f};
        #pragma unroll
        for (int k0 = 0; k0 < 64; k0 += 32) {
            bf16x8 a = *(const bf16x8*)(Pbf + (wm + fr) * 72 + k0 + kq);
            #pragma unroll
            for (int t = 0; t < 4; ++t) {
                bf16x8 bv = *(const bf16x8*)(Vt + (wn2 + t * 16 + fr) * 72 + k0 + kq);
                o[t] = __builtin_amdgcn_mfma_f32_16x16x32_bf16(a, bv, o[t], 0, 0, 0);
            }
        }
        #pragma unroll
        for (int t = 0; t < 4; ++t)
            #pragma unroll
            for (int r = 0; r < 4; ++r) {
                size_t m = (size_t)b * 64 + half * 32 + wm + crow + r;
                int col = h * 128 + wn2 + t * 16 + ccol;
                x1o[m * 1024 + 512 + col] = f2bf(o[t][r]);
            }
    }
}

// ---------------------------------------------------------------------------
// Fused fc1 GEMM (blocks 0-511) + pair MLPs (blocks 512-2559).
// fc1: u = relu([x1|o] @ [W1a|Wc]^T + b_eff), M=2048 N=512 K=1024, BM=32.
// ---------------------------------------------------------------------------
__global__ __launch_bounds__(256)
void w1pair(const unsigned short* __restrict__ x1o,
            const unsigned short* __restrict__ W1cb,
            const float* __restrict__ beff, float* __restrict__ u,
            const unsigned short* __restrict__ Pb,
            const float* __restrict__ a1, const float* __restrict__ pws,
            const float* __restrict__ d1b1, const float* __restrict__ d1w2,
            const float* __restrict__ d1b2, const float* __restrict__ d2b1,
            const float* __restrict__ d2w2, const float* __restrict__ d2b2,
            float* __restrict__ x2_attn, float* __restrict__ out1,
            float* __restrict__ out2) {
    __shared__ unsigned short Asl[32 * 64];
    __shared__ unsigned short Bsl[64 * 64];
    const int bx = blockIdx.x, tid = threadIdx.x;
    const int wave = tid >> 6, lane = tid & 63;

    if (bx < 512) {
        const int m0 = (bx >> 3) * 32, n0 = (bx & 7) * 64;
        const int wm = (wave >> 1) * 16, wn = (wave & 1) * 32;
        const int fr = lane & 15, kq4 = lane >> 4;
        f32x4 acc[2] = {};
        for (int k0 = 0; k0 < 1024; k0 += 64) {
            {
                int r = tid >> 3, q = tid & 7;
                int col = (q ^ (r & 7)) * 8;
                __builtin_amdgcn_global_load_lds(
                    (cv_global*)(x1o + (size_t)(m0 + r) * 1024 + k0 + col),
                    (v_lds*)(Asl + wave * 512), 16, 0, 0);
            }
            #pragma unroll
            for (int c0 = 0; c0 < 512; c0 += 256) {
                int cc = c0 + tid, r = cc >> 3, q = cc & 7;
                int col = (q ^ (r & 7)) * 8;
                __builtin_amdgcn_global_load_lds(
                    (cv_global*)(W1cb + (size_t)(n0 + r) * 1024 + k0 + col),
                    (v_lds*)(Bsl + c0 * 8 + wave * 512), 16, 0, 0);
            }
            __syncthreads();
            #pragma unroll
            for (int j = 0; j < 2; ++j) {
                int kc = kq4 + j * 4;
                int rb0 = wn + fr, rb1 = wn + 16 + fr, ra = wm + fr;
                bf16x8 b0 = *(const bf16x8*)(Bsl + rb0 * 64 + (kc ^ (rb0 & 7)) * 8);
                bf16x8 b1 = *(const bf16x8*)(Bsl + rb1 * 64 + (kc ^ (rb1 & 7)) * 8);
                bf16x8 af = *(const bf16x8*)(Asl + ra * 64 + (kc ^ (ra & 7)) * 8);
                acc[0] = __builtin_amdgcn_mfma_f32_16x16x32_bf16(af, b0, acc[0], 0, 0, 0);
                acc[1] = __builtin_amdgcn_mfma_f32_16x16x32_bf16(af, b1, acc[1], 0, 0, 0);
            }
            __syncthreads();
        }
        const int crow = (lane >> 4) * 4, ccol = lane & 15;
        #pragma unroll
        for (int c = 0; c < 2; ++c) {
            int n = n0 + wn + c * 16 + ccol;
            float bj = beff[n];
            #pragma unroll
            for (int i = 0; i < 4; ++i) {
                size_t m = (size_t)(m0 + wm + crow + i);
                u[m * 512 + n] = fmaxf(acc[c][i] + bj, 0.f);
            }
        }
    } else {
        const int idx = bx - 512;
        const int f = idx & 63, b = idx >> 6;
        const size_t row = (size_t)b * SS + f;
        const int c0 = lane * 2, c1 = lane * 2 + 1;

        const float p1f0 = bf2f(Pb[row * 256 + c0]),       p1f1 = bf2f(Pb[row * 256 + c1]);
        const float p2f0 = bf2f(Pb[row * 256 + 128 + c0]), p2f1 = bf2f(Pb[row * 256 + 128 + c1]);
        const float w10 = d1w2[c0], w11 = d1w2[c1];
        const float w20 = d2w2[c0], w21 = d2w2[c1];
        const float b10 = d1b1[c0], b11 = d1b1[c1];
        const float b20 = d2b1[c0], b21 = d2b1[c1];
        const float bb1 = d1b2[0], bb2 = d2b2[0];

        const float* a1r = a1 + row * SS;
        const float* ph0 = pws + (((size_t)b * 4 + 0) * 64 + f) * 64;
        const float* ph1 = pws + (((size_t)b * 4 + 1) * 64 + f) * 64;
        const float* ph2 = pws + (((size_t)b * 4 + 2) * 64 + f) * 64;
        const float* ph3 = pws + (((size_t)b * 4 + 3) * 64 + f) * 64;
        const size_t bbase = (size_t)b * SS * 256;

        for (int g = wave; g < 64; g += 4) {
            float aa1 = a1r[g];
            float aa2 = 0.25f * (ph0[g] + ph1[g] + ph2[g] + ph3[g]);
            float q10 = bf2f(Pb[bbase + g * 256 + c0]);
            float q11 = bf2f(Pb[bbase + g * 256 + c1]);
            float q20 = bf2f(Pb[bbase + g * 256 + 128 + c0]);
            float q21 = bf2f(Pb[bbase + g * 256 + 128 + c1]);
            float h10 = fmaxf(aa1 * (q10 - p1f0) + b10, 0.f);
            float h11 = fmaxf(aa1 * (q11 - p1f1) + b11, 0.f);
            float h20 = fmaxf(aa2 * (q20 - p2f0) + b20, 0.f);
            float h21 = fmaxf(aa2 * (q21 - p2f1) + b21, 0.f);
            float s1 = w10 * h10 + w11 * h11;
            float s2 = w20 * h20 + w21 * h21;
            #pragma unroll
            for (int m = 32; m; m >>= 1) {
                s1 += __shfl_xor(s1, m);
                s2 += __shfl_xor(s2, m);
            }
            if (lane == 0) {
                x2_attn[row * SS + g] = aa2;
                out1[row * SS + g] = fmaxf(s1 + bb1, 0.f);
                out2[row * SS + g] = fmaxf(s2 + bb2, 0.f);
            }
        }
    }
}

// ---------------------------------------------------------------------------
// bf16 MFMA GEMM (BM=32), used for fc2. Same structure as w1pair GEMM part.
// ---------------------------------------------------------------------------
__global__ __launch_bounds__(256)
void gemm_w2(const unsigned short* __restrict__ A,
             const unsigned short* __restrict__ B,
             const float* __restrict__ bias, float* __restrict__ C) {
    __shared__ unsigned short Asl[32 * 64];
    __shared__ unsigned short Bsl[64 * 64];
    const int tid = threadIdx.x, wave = tid >> 6, lane = tid & 63;
    const int m0 = blockIdx.y * 32, n0 = blockIdx.x * 64;
    const int wm = (wave >> 1) * 16, wn = (wave & 1) * 32;
    const int fr = lane & 15, kq4 = lane >> 4;
    f32x4 acc[2] = {};
    for (int k0 = 0; k0 < 512; k0 += 64) {
        {
            int r = tid >> 3, q = tid & 7;
            int col = (q ^ (r & 7)) * 8;
            __builtin_amdgcn_global_load_lds(
                (cv_global*)(A + (size_t)(m0 + r) * 512 + k0 + col),
                (v_lds*)(Asl + wave * 512), 16, 0, 0);
        }
        #pragma unroll
        for (int c0 = 0; c0 < 512; c0 += 256) {
            int cc = c0 + tid, r = cc >> 3, q = cc & 7;
            int col = (q ^ (r & 7)) * 8;
            __builtin_amdgcn_global_load_lds(
                (cv_global*)(B + (size_t)(n0 + r) * 512 + k0 + col),
                (v_lds*)(Bsl + c0 * 8 + wave * 512), 16, 0, 0);
        }
        __syncthreads();
        #pragma unroll
        for (int j = 0; j < 2; ++j) {
            int kc = kq4 + j * 4;
            int rb0 = wn + fr, rb1 = wn + 16 + fr, ra = wm + fr;
            bf16x8 b0 = *(const bf16x8*)(Bsl + rb0 * 64 + (kc ^ (rb0 & 7)) * 8);
            bf16x8 b1 = *(const bf16x8*)(Bsl + rb1 * 64 + (kc ^ (rb1 & 7)) * 8);
            bf16x8 af = *(const bf16x8*)(Asl + ra * 64 + (kc ^ (ra & 7)) * 8);
            acc[0] = __builtin_amdgcn_mfma_f32_16x16x32_bf16(af, b0, acc[0], 0, 0, 0);
            acc[1] = __builtin_amdgcn_mfma_f32_16x16x32_bf16(af, b1, acc[1], 0, 0, 0);
        }
        __syncthreads();
    }
    const int crow = (lane >> 4) * 4, ccol = lane & 15;
    #pragma unroll
    for (int c = 0; c < 2; ++c) {
        int n = n0 + wn + c * 16 + ccol;
        float bj = bias[n];
        #pragma unroll
        for (int i = 0; i < 4; ++i) {
            size_t m = (size_t)(m0 + wm + crow + i);
            C[m * 512 + n] = fmaxf(acc[c][i] + bj, 0.f);
        }
    }
}

// ---------------------------------------------------------------------------
// out = LayerNorm(base + u) * g + be (+ optional bf16 copy).
// ---------------------------------------------------------------------------
__global__ __launch_bounds__(256)
void add_ln(const float* __restrict__ base, const float* __restrict__ u,
            const float* __restrict__ gam, const float* __restrict__ bet,
            float* __restrict__ out, unsigned short* __restrict__ outb) {
    const int row = blockIdx.x;
    const int tid = threadIdx.x, wave = tid >> 6, lane = tid & 63;
    const float* br = base + (size_t)row * EE;
    const float* ur = u + (size_t)row * EE;
    float t0 = br[tid] + ur[tid];
    float t1 = br[tid + 256] + ur[tid + 256];
    float s = t0 + t1, sq = t0 * t0 + t1 * t1;
    #pragma unroll
    for (int m = 32; m; m >>= 1) {
        s += __shfl_xor(s, m);
        sq += __shfl_xor(sq, m);
    }
    __shared__ float ssum[4], ssq[4];
    if (lane == 0) { ssum[wave] = s; ssq[wave] = sq; }
    __syncthreads();
    s = ssum[0] + ssum[1] + ssum[2] + ssum[3];
    sq = ssq[0] + ssq[1] + ssq[2] + ssq[3];
    float mean = s * (1.0f / EE);
    float var = sq * (1.0f / EE) - mean * mean;
    float inv = rsqrtf(var + LNEPS);
    float v0 = (t0 - mean) * inv * gam[tid] + bet[tid];
    float v1 = (t1 - mean) * inv * gam[tid + 256] + bet[tid + 256];
    float* orow = out + (size_t)row * EE;
    orow[tid] = v0;
    orow[tid + 256] = v1;
    if (outb) {
        unsigned short* obr = outb + (size_t)row * EE;
        obr[tid] = f2bf(v0);
        obr[tid + 256] = f2bf(v1);
    }
}

// ---------------------------------------------------------------------------
extern "C" void kernel_launch(void* const* d_in, const int* in_sizes, int n_in,
                              void* d_out, int out_size, void* d_ws,
                              size_t ws_size, hipStream_t stream) {
    const float* x    = (const float*)d_in[0];
    const float* Wqkv = (const float*)d_in[1];
    const float* bqkv = (const float*)d_in[2];
    const float* Wo   = (const float*)d_in[3];
    const float* bo   = (const float*)d_in[4];
    const float* W1   = (const float*)d_in[5];
    const float* b1   = (const float*)d_in[6];
    const float* W2   = (const float*)d_in[7];
    const float* b2   = (const float*)d_in[8];
    const float* g1   = (const float*)d_in[9];
    const float* be1  = (const float*)d_in[10];
    const float* g2   = (const float*)d_in[11];
    const float* be2  = (const float*)d_in[12];
    const float* d1W1 = (const float*)d_in[13];
    const float* d1b1 = (const float*)d_in[14];
    const float* d1W2 = (const float*)d_in[15];
    const float* d1b2 = (const float*)d_in[16];
    const float* d2W1 = (const float*)d_in[17];
    const float* d2b1 = (const float*)d_in[18];
    const float* d2W2 = (const float*)d_in[19];
    const float* d2b2 = (const float*)d_in[20];

    float* out      = (float*)d_out;
    float* out_main = out;
    float* x1_attn  = out + 1048576;
    float* x2_attn  = out + 1048576 + 131072;
    float* diff1    = out + 1048576 + 2 * 131072;
    float* diff2    = out + 1048576 + 3 * 131072;

    float* ws    = (float*)d_ws;
    float* u_buf = ws;                   // 2048*512
    float* h_buf = ws + 1048576;         // 2048*512
    float* pws   = ws + 2097152;         // 32*4*64*64
    float* b_eff = ws + 2621440;         // 512
    unsigned short* bb = (unsigned short*)(ws + 2621952);

    unsigned short* xb    = bb + XB_O;
    unsigned short* Wfull = bb + WFULL_O;
    unsigned short* W1cb  = bb + W1CB_O;
    unsigned short* W2b   = bb + W2B_O;
    unsigned short* qkvb  = bb + QKVB_O;
    unsigned short* x1o   = bb + X1O_O;
    unsigned short* hb    = bb + HB_O;
    unsigned short* Pb    = bb + PB_O;

    // 1: convert + Wc prep + b_eff + L2-attention/x1 (all input-only deps)
    mega1<<<3524, 256, 0, stream>>>(x, Wqkv, Wo, W1, W2, d1W1, d2W1, b1, bo,
                                    bb, b_eff, x1_attn);

    // 2: [qkv | P] = xb @ Wfull^T : M=2048 N=1792 K=512
    gemm_qkvp<<<dim3(28, 32), 256, 0, stream>>>(xb, Wfull, bqkv, qkvb, Pb);

    // 3: attention; o -> x1o[:,512:], probs -> pws
    mha_attn<<<dim3(8, 32), 256, 0, stream>>>(qkvb, x1o, pws);

    // 4: u = relu([x1|o] @ [W1a|Wc]^T + b_eff)  +  pair MLPs
    w1pair<<<2560, 256, 0, stream>>>(x1o, W1cb, b_eff, u_buf, Pb, x1_attn, pws,
                                     d1b1, d1W2, d1b2, d2b1, d2W2, d2b2,
                                     x2_attn, diff1, diff2);

    // 5: h = LN(x + u) -> h_buf (f32) + hb (bf16)
    add_ln<<<2048, 256, 0, stream>>>(x, u_buf, g1, be1, h_buf, hb);

    // 6: u = relu(h @ W2^T + b2)
    gemm_w2<<<dim3(8, 64), 256, 0, stream>>>(hb, W2b, b2, u_buf);

    // 7: out = LN(h + u)
    add_ln<<<2048, 256, 0, stream>>>(h_buf, u_buf, g2, be2, out_main, nullptr);
}

// Round 6
// 178.971 us; speedup vs baseline: 3.1002x; 1.0683x over previous
//
#include <hip/hip_runtime.h>
#include <math.h>

// Problem constants
#define SS 64
#define EE 512
#define L2T 13.544f
#define LNEPS 1e-5f

using bf16x8 = __attribute__((ext_vector_type(8))) __bf16;
using u16x8  = __attribute__((ext_vector_type(8))) unsigned short;
using f32x4  = __attribute__((ext_vector_type(4))) float;

typedef const void __attribute__((address_space(1))) cv_global;
typedef void __attribute__((address_space(3))) v_lds;

__device__ inline unsigned short f2bf(float f) {
    union { float f; unsigned u; } v; v.f = f;
    unsigned r = v.u + 0x7fff + ((v.u >> 16) & 1);
    return (unsigned short)(r >> 16);
}
__device__ inline float bf2f(unsigned short h) {
    union { unsigned u; float f; } v; v.u = (unsigned)h << 16;
    return v.f;
}

#define MFMA16 __builtin_amdgcn_mfma_f32_16x16x32_bf16

// ---- workspace layout -------------------------------------------------------
// f32: u_buf@0 (1048576), h_buf@1048576, pws@2097152 (524288), b_eff@2621440
//      (512), Pl2 (bf16 l2-probs, 2048x64 u16 = 65536 f32) @2621952.
// bb (ushort) starts at f32 2687488:
#define XB_O    0
#define WFULL_O 1048576
#define W1CB_O  1966080
#define W2B_O   2490368
#define QKVB_O  2752512
#define X1O_O   5898240
#define HB_O    7995392
#define PB_O    9043968

// ---------------------------------------------------------------------------
// MEGA-1: weight convert (0-1407) + Wc=W1b@Wo prep (1408-1471) + b_eff
// (1472-1475) + Gram-based L2 attention (1476-1507, one block per batch).
// L2 path: bf16x3 Gram via MFMA; d2 = Gff+Ggg-2Gfg (diag cancels exactly);
// fp32 softmax -> x1_attn (f32 out) + Pl2 (bf16 probs); also emits xb=bf16(x).
// ---------------------------------------------------------------------------
__global__ __launch_bounds__(256)
void mega1(const float* __restrict__ x, const float* __restrict__ Wqkv,
           const float* __restrict__ Wo, const float* __restrict__ W1,
           const float* __restrict__ W2, const float* __restrict__ d1,
           const float* __restrict__ d2, const float* __restrict__ b1,
           const float* __restrict__ bo, unsigned short* __restrict__ bb,
           float* __restrict__ b_eff, float* __restrict__ x1_attn,
           unsigned short* __restrict__ Pl2) {
    const int bx = blockIdx.x, tid = threadIdx.x;
    __shared__ __align__(16) char smem[36096];

    if (bx < 1408) {
        // ---- convert weights to bf16 (float4-vectorized) ----
        int i = bx * 256 + tid;
        ushort4* dst4 = (ushort4*)bb;
        const float4* s; int di;
        if (i < 196608)      { s = (const float4*)Wqkv + i;          di = WFULL_O/4 + i; }
        else if (i < 212992) { int j = i-196608; s = (const float4*)d1 + j; di = WFULL_O/4 + 196608 + j; }
        else if (i < 229376) { int j = i-212992; s = (const float4*)d2 + j; di = WFULL_O/4 + 212992 + j; }
        else if (i < 294912) { int j = i-229376; s = (const float4*)W2 + j; di = W2B_O/4 + j; }
        else                 { int j = i-294912; int r = j>>7, cq = j&127;
                               s = (const float4*)W1 + r*256 + cq;   di = W1CB_O/4 + r*256 + cq; }
        float4 v = *s;
        ushort4 o;
        o.x = f2bf(v.x); o.y = f2bf(v.y); o.z = f2bf(v.z); o.w = f2bf(v.w);
        dst4[di] = o;
    } else if (bx < 1472) {
        // ---- prep: Wc[m,j] = sum_k W1b[m,k] * Wo[k,j], 64x64 tiles ----
        const int tb = bx - 1408;
        const int m0 = (tb >> 3) * 64, n0 = (tb & 7) * 64;
        unsigned short* Asl = (unsigned short*)smem;   // [64][40]
        unsigned short* Bsl = Asl + 64 * 40;           // [64][40]
        const int wave = tid >> 6, lane = tid & 63;
        const int wm = (wave >> 1) * 32, wn = (wave & 1) * 32;
        const int fr = lane & 15, kq = (lane >> 4) * 8;
        f32x4 acc[2][2] = {};
        for (int k0 = 0; k0 < 512; k0 += 32) {
            {
                int m = tid >> 2, kk = (tid & 3) * 8;
                const float* src = W1 + (size_t)(m0 + m) * 1024 + 512 + k0 + kk;
                float4 v0 = *(const float4*)src, v1 = *(const float4*)(src + 4);
                u16x8 t = {f2bf(v0.x), f2bf(v0.y), f2bf(v0.z), f2bf(v0.w),
                           f2bf(v1.x), f2bf(v1.y), f2bf(v1.z), f2bf(v1.w)};
                *(u16x8*)(Asl + m * 40 + kk) = t;
            }
            {
                int k = tid >> 3, jq = (tid & 7) * 8;
                const float* src = Wo + (size_t)(k0 + k) * 512 + n0 + jq;
                float4 v0 = *(const float4*)src, v1 = *(const float4*)(src + 4);
                float vv[8] = {v0.x, v0.y, v0.z, v0.w, v1.x, v1.y, v1.z, v1.w};
                #pragma unroll
                for (int e = 0; e < 8; ++e) Bsl[(jq + e) * 40 + k] = f2bf(vv[e]);
            }
            __syncthreads();
            bf16x8 a0 = *(const bf16x8*)(Asl + (wm + fr) * 40 + kq);
            bf16x8 a1 = *(const bf16x8*)(Asl + (wm + 16 + fr) * 40 + kq);
            bf16x8 b0 = *(const bf16x8*)(Bsl + (wn + fr) * 40 + kq);
            bf16x8 b1 = *(const bf16x8*)(Bsl + (wn + 16 + fr) * 40 + kq);
            acc[0][0] = MFMA16(a0, b0, acc[0][0], 0, 0, 0);
            acc[0][1] = MFMA16(a0, b1, acc[0][1], 0, 0, 0);
            acc[1][0] = MFMA16(a1, b0, acc[1][0], 0, 0, 0);
            acc[1][1] = MFMA16(a1, b1, acc[1][1], 0, 0, 0);
            __syncthreads();
        }
        unsigned short* W1cb = bb + W1CB_O;
        const int crow = (lane >> 4) * 4, ccol = lane & 15;
        #pragma unroll
        for (int r2 = 0; r2 < 2; ++r2)
            #pragma unroll
            for (int c2 = 0; c2 < 2; ++c2)
                #pragma unroll
                for (int i = 0; i < 4; ++i) {
                    int m = m0 + wm + r2 * 16 + crow + i;
                    int j = n0 + wn + c2 * 16 + ccol;
                    W1cb[(size_t)m * 1024 + 512 + j] = f2bf(acc[r2][c2][i]);
                }
    } else if (bx < 1476) {
        // ---- b_eff[n] = b1[n] + sum_k W1b[n,k]*bo[k] ----
        int n = (bx - 1472) * 128 + (tid >> 1);
        int kh = (tid & 1) * 256;
        float s = 0.f;
        for (int k = 0; k < 256; ++k)
            s += W1[(size_t)n * 1024 + 512 + kh + k] * bo[kh + k];
        s += __shfl_xor(s, 1);
        if ((tid & 1) == 0) b_eff[n] = b1[n] + s;
    } else {
        // ---- Gram-based L2 attention, one block per batch b ----
        const int b = bx - 1476;
        unsigned short* Xhi = (unsigned short*)smem;   // [64][72]
        unsigned short* Xlo = Xhi + 64 * 72;           // [64][72]
        float* sc    = (float*)(Xlo + 64 * 72);        // [64][68]
        float* norms = sc + 64 * 68;                   // [64]
        const int wave = tid >> 6, lane = tid & 63;
        const int wm = (wave >> 1) * 32, wn = (wave & 1) * 32;
        const int fr = lane & 15;
        const int srow = tid >> 2, scq = (tid & 3) * 16;

        f32x4 acc[2][2] = {};
        const float* xrow = x + (size_t)b * 32768;
        unsigned short* xbg = bb + XB_O + (size_t)b * 32768;

        for (int k0 = 0; k0 < 512; k0 += 64) {
            const float* src = xrow + srow * 512 + k0 + scq;
            u16x8 hi0, hi1, lo0, lo1;
            #pragma unroll
            for (int e = 0; e < 8; ++e) {
                float v = src[e];
                unsigned short h = f2bf(v);
                hi0[e] = h; lo0[e] = f2bf(v - bf2f(h));
            }
            #pragma unroll
            for (int e = 0; e < 8; ++e) {
                float v = src[8 + e];
                unsigned short h = f2bf(v);
                hi1[e] = h; lo1[e] = f2bf(v - bf2f(h));
            }
            *(u16x8*)(Xhi + srow * 72 + scq)     = hi0;
            *(u16x8*)(Xhi + srow * 72 + scq + 8) = hi1;
            *(u16x8*)(Xlo + srow * 72 + scq)     = lo0;
            *(u16x8*)(Xlo + srow * 72 + scq + 8) = lo1;
            *(u16x8*)(xbg + srow * 512 + k0 + scq)     = hi0;
            *(u16x8*)(xbg + srow * 512 + k0 + scq + 8) = hi1;
            __syncthreads();
            #pragma unroll
            for (int j = 0; j < 2; ++j) {
                int kk = j * 32 + (lane >> 4) * 8;
                bf16x8 ah0 = *(const bf16x8*)(Xhi + (wm + fr) * 72 + kk);
                bf16x8 ah1 = *(const bf16x8*)(Xhi + (wm + 16 + fr) * 72 + kk);
                bf16x8 bh0 = *(const bf16x8*)(Xhi + (wn + fr) * 72 + kk);
                bf16x8 bh1 = *(const bf16x8*)(Xhi + (wn + 16 + fr) * 72 + kk);
                bf16x8 al0 = *(const bf16x8*)(Xlo + (wm + fr) * 72 + kk);
                bf16x8 al1 = *(const bf16x8*)(Xlo + (wm + 16 + fr) * 72 + kk);
                bf16x8 bl0 = *(const bf16x8*)(Xlo + (wn + fr) * 72 + kk);
                bf16x8 bl1 = *(const bf16x8*)(Xlo + (wn + 16 + fr) * 72 + kk);
                acc[0][0] = MFMA16(ah0, bh0, acc[0][0], 0, 0, 0);
                acc[0][0] = MFMA16(ah0, bl0, acc[0][0], 0, 0, 0);
                acc[0][0] = MFMA16(al0, bh0, acc[0][0], 0, 0, 0);
                acc[0][1] = MFMA16(ah0, bh1, acc[0][1], 0, 0, 0);
                acc[0][1] = MFMA16(ah0, bl1, acc[0][1], 0, 0, 0);
                acc[0][1] = MFMA16(al0, bh1, acc[0][1], 0, 0, 0);
                acc[1][0] = MFMA16(ah1, bh0, acc[1][0], 0, 0, 0);
                acc[1][0] = MFMA16(ah1, bl0, acc[1][0], 0, 0, 0);
                acc[1][0] = MFMA16(al1, bh0, acc[1][0], 0, 0, 0);
                acc[1][1] = MFMA16(ah1, bh1, acc[1][1], 0, 0, 0);
                acc[1][1] = MFMA16(ah1, bl1, acc[1][1], 0, 0, 0);
                acc[1][1] = MFMA16(al1, bh1, acc[1][1], 0, 0, 0);
            }
            __syncthreads();
        }
        const int crow = (lane >> 4) * 4, ccol = lane & 15;
        #pragma unroll
        for (int r2 = 0; r2 < 2; ++r2)
            #pragma unroll
            for (int c2 = 0; c2 < 2; ++c2)
                #pragma unroll
                for (int i = 0; i < 4; ++i)
                    sc[(wm + r2 * 16 + crow + i) * 68 + wn + c2 * 16 + ccol] =
                        acc[r2][c2][i];
        __syncthreads();
        if (tid < 64) norms[tid] = sc[tid * 68 + tid];
        __syncthreads();
        #pragma unroll
        for (int i = 0; i < 16; ++i) {
            int f = wave * 16 + i;
            float nf = norms[f];
            // logit = -(nf + ng - 2*G)/L2T; diagonal cancels exactly
            float val = (2.f * sc[f * 68 + lane] - nf - norms[lane]) * (1.0f / L2T);
            float mx = val;
            #pragma unroll
            for (int m = 32; m; m >>= 1) mx = fmaxf(mx, __shfl_xor(mx, m));
            float e = expf(val - mx);
            float sum = e;
            #pragma unroll
            for (int m = 32; m; m >>= 1) sum += __shfl_xor(sum, m);
            float a = e / sum;
            x1_attn[((size_t)b * 64 + f) * 64 + lane] = a;
            Pl2[((size_t)b * 64 + f) * 64 + lane] = f2bf(a);
        }
    }
}

// ---------------------------------------------------------------------------
// Fused qkv + P GEMM + x1-apply.  Wfull = [Wqkv(1536) ; d1W1 ; d2W1].
// bx<24 -> qkvb; 24<=bx<28 -> Pb; bx>=28 -> x1 = Pl2 @ xb (per (b, e-tile)).
// ---------------------------------------------------------------------------
__global__ __launch_bounds__(256)
void gemm_qkvp(const unsigned short* __restrict__ A,
               const unsigned short* __restrict__ B,
               const float* __restrict__ bias,
               unsigned short* __restrict__ Cq, unsigned short* __restrict__ Cp,
               const unsigned short* __restrict__ Pl2,
               unsigned short* __restrict__ x1o) {
    __shared__ unsigned short qsm[8704];   // GEMM: Asl@0, Bsl@4096; x1: Ap/Xt
    const int tid = threadIdx.x, wave = tid >> 6, lane = tid & 63;
    const int fr = lane & 15;
    const int crow = (lane >> 4) * 4, ccol = lane & 15;

    if (blockIdx.x < 28) {
        unsigned short* Asl = qsm;
        unsigned short* Bsl = qsm + 4096;
        const int m0 = blockIdx.y * 64, n0 = blockIdx.x * 64;
        const int wm = (wave >> 1) * 32, wn = (wave & 1) * 32;
        const int kq4 = lane >> 4;
        f32x4 acc[2][2] = {};

        for (int k0 = 0; k0 < 512; k0 += 64) {
            #pragma unroll
            for (int c0 = 0; c0 < 512; c0 += 256) {
                int cc = c0 + tid, r = cc >> 3, q = cc & 7;
                int col = (q ^ (r & 7)) * 8;
                __builtin_amdgcn_global_load_lds(
                    (cv_global*)(A + (size_t)(m0 + r) * 512 + k0 + col),
                    (v_lds*)(Asl + c0 * 8 + wave * 512), 16, 0, 0);
            }
            #pragma unroll
            for (int c0 = 0; c0 < 512; c0 += 256) {
                int cc = c0 + tid, r = cc >> 3, q = cc & 7;
                int col = (q ^ (r & 7)) * 8;
                __builtin_amdgcn_global_load_lds(
                    (cv_global*)(B + (size_t)(n0 + r) * 512 + k0 + col),
                    (v_lds*)(Bsl + c0 * 8 + wave * 512), 16, 0, 0);
            }
            __syncthreads();
            #pragma unroll
            for (int j = 0; j < 2; ++j) {
                int kc = kq4 + j * 4;
                int rb0 = wn + fr, rb1 = wn + 16 + fr;
                bf16x8 b0 = *(const bf16x8*)(Bsl + rb0 * 64 + (kc ^ (rb0 & 7)) * 8);
                bf16x8 b1 = *(const bf16x8*)(Bsl + rb1 * 64 + (kc ^ (rb1 & 7)) * 8);
                #pragma unroll
                for (int r = 0; r < 2; ++r) {
                    int ra = wm + r * 16 + fr;
                    bf16x8 af = *(const bf16x8*)(Asl + ra * 64 + (kc ^ (ra & 7)) * 8);
                    acc[r][0] = MFMA16(af, b0, acc[r][0], 0, 0, 0);
                    acc[r][1] = MFMA16(af, b1, acc[r][1], 0, 0, 0);
                }
            }
            __syncthreads();
        }

        if (blockIdx.x < 24) {
            float bj0 = bias[n0 + wn + ccol], bj1 = bias[n0 + wn + 16 + ccol];
            #pragma unroll
            for (int r = 0; r < 2; ++r)
                #pragma unroll
                for (int c = 0; c < 2; ++c) {
                    float bj = c ? bj1 : bj0;
                    #pragma unroll
                    for (int i = 0; i < 4; ++i) {
                        size_t m = (size_t)(m0 + wm + r * 16 + crow + i);
                        int n = n0 + wn + c * 16 + ccol;
                        Cq[m * 1536 + n] = f2bf(acc[r][c][i] + bj);
                    }
                }
        } else {
            int p0 = n0 - 1536;
            #pragma unroll
            for (int r = 0; r < 2; ++r)
                #pragma unroll
                for (int c = 0; c < 2; ++c)
                    #pragma unroll
                    for (int i = 0; i < 4; ++i) {
                        size_t m = (size_t)(m0 + wm + r * 16 + crow + i);
                        int n = p0 + wn + c * 16 + ccol;
                        Cp[m * 256 + n] = f2bf(acc[r][c][i]);
                    }
        }
    } else {
        // ---- x1[b, f, e0:e0+64] = sum_g Pl2[b,f,g] * xb[b,g,e] ----
        const int e0 = (blockIdx.x - 28) * 64;
        const int b = blockIdx.y;
        unsigned short* Ap = qsm;            // [64][68] probs row-major
        unsigned short* Xt = qsm + 64 * 68;  // [64][68] X^T tile: Xt[e][g]
        {
            int row = tid >> 2, cq = (tid & 3) * 16;
            const unsigned short* src = Pl2 + (size_t)b * 4096 + row * 64 + cq;
            *(u16x8*)(Ap + row * 68 + cq)     = *(const u16x8*)src;
            *(u16x8*)(Ap + row * 68 + cq + 8) = *(const u16x8*)(src + 8);
        }
        {
            int g = tid >> 2, cq = (tid & 3) * 16;
            const unsigned short* src = A + (size_t)b * 32768 + g * 512 + e0 + cq;
            u16x8 v0 = *(const u16x8*)src, v1 = *(const u16x8*)(src + 8);
            #pragma unroll
            for (int e = 0; e < 8; ++e) Xt[(cq + e) * 68 + g] = v0[e];
            #pragma unroll
            for (int e = 0; e < 8; ++e) Xt[(cq + 8 + e) * 68 + g] = v1[e];
        }
        __syncthreads();
        const int wm2 = wave * 16;
        f32x4 o[4] = {};
        #pragma unroll
        for (int j = 0; j < 2; ++j) {
            int kk = j * 32 + (lane >> 4) * 8;
            bf16x8 a = *(const bf16x8*)(Ap + (wm2 + fr) * 68 + kk);
            #pragma unroll
            for (int t = 0; t < 4; ++t) {
                bf16x8 bv = *(const bf16x8*)(Xt + (t * 16 + fr) * 68 + kk);
                o[t] = MFMA16(a, bv, o[t], 0, 0, 0);
            }
        }
        #pragma unroll
        for (int t = 0; t < 4; ++t)
            #pragma unroll
            for (int i = 0; i < 4; ++i) {
                size_t m = (size_t)b * 64 + wm2 + crow + i;
                x1o[m * 1024 + e0 + t * 16 + ccol] = f2bf(o[t][i]);
            }
    }
}

// ---------------------------------------------------------------------------
// MFMA attention. Block per (b, h, half). o written straight into x1o[:,512:].
// ---------------------------------------------------------------------------
__global__ __launch_bounds__(256)
void mha_attn(const unsigned short* __restrict__ qkv,
              unsigned short* __restrict__ x1o, float* __restrict__ pws) {
    const int hh = blockIdx.x;
    const int h = hh >> 1, half = hh & 1;
    const int b = blockIdx.y;
    const int tid = threadIdx.x, wave = tid >> 6, lane = tid & 63;

    __shared__ unsigned short Qs[32 * 136];
    __shared__ unsigned short Ks[64 * 136];
    __shared__ unsigned short Vt[128 * 72];
    __shared__ float sc[32 * 68];
    __shared__ unsigned short Pbf[32 * 72];

    const unsigned short* base = qkv + (size_t)b * 64 * 1536;
    {
        int row = tid >> 3, col = (tid & 7) * 16;
        const unsigned short* src = base + (half * 32 + row) * 1536 + h * 128 + col;
        *(u16x8*)(Qs + row * 136 + col)     = *(const u16x8*)(src);
        *(u16x8*)(Qs + row * 136 + col + 8) = *(const u16x8*)(src + 8);
    }
    {
        int row = tid >> 2, col = (tid & 3) * 32;
        const unsigned short* src = base + row * 1536 + 512 + h * 128 + col;
        #pragma unroll
        for (int j = 0; j < 4; ++j)
            *(u16x8*)(Ks + row * 136 + col + j * 8) = *(const u16x8*)(src + j * 8);
    }
    {
        int g = tid >> 2, col = (tid & 3) * 32;
        const unsigned short* src = base + g * 1536 + 1024 + h * 128 + col;
        #pragma unroll
        for (int j = 0; j < 4; ++j) {
            u16x8 v = *(const u16x8*)(src + j * 8);
            #pragma unroll
            for (int e = 0; e < 8; ++e)
                Vt[(col + j * 8 + e) * 72 + g] = v[e];
        }
    }
    __syncthreads();

    const int fr = lane & 15, kq = (lane >> 4) * 8;
    const int crow = (lane >> 4) * 4, ccol = lane & 15;
    const int wm = (wave >> 1) * 16;
    {
        const int wn = (wave & 1) * 32;
        f32x4 s0 = {0.f, 0.f, 0.f, 0.f}, s1 = s0;
        #pragma unroll
        for (int k0 = 0; k0 < 128; k0 += 32) {
            bf16x8 a  = *(const bf16x8*)(Qs + (wm + fr) * 136 + k0 + kq);
            bf16x8 b0 = *(const bf16x8*)(Ks + (wn + fr) * 136 + k0 + kq);
            bf16x8 b1 = *(const bf16x8*)(Ks + (wn + 16 + fr) * 136 + k0 + kq);
            s0 = MFMA16(a, b0, s0, 0, 0, 0);
            s1 = MFMA16(a, b1, s1, 0, 0, 0);
        }
        const float scale = 0.08838834764831845f;
        #pragma unroll
        for (int r = 0; r < 4; ++r) {
            sc[(wm + crow + r) * 68 + wn + ccol]      = s0[r] * scale;
            sc[(wm + crow + r) * 68 + wn + 16 + ccol] = s1[r] * scale;
        }
    }
    __syncthreads();

    #pragma unroll
    for (int i = 0; i < 8; ++i) {
        int f = wave * 8 + i;
        float v = sc[f * 68 + lane];
        float mx = v;
        #pragma unroll
        for (int m = 32; m; m >>= 1) mx = fmaxf(mx, __shfl_xor(mx, m));
        float e = expf(v - mx);
        float sum = e;
        #pragma unroll
        for (int m = 32; m; m >>= 1) sum += __shfl_xor(sum, m);
        float a = e / sum;
        Pbf[f * 72 + lane] = f2bf(a);
        pws[(((size_t)b * 4 + h) * 64 + half * 32 + f) * 64 + lane] = a;
    }
    __syncthreads();

    {
        const int wn2 = (wave & 1) * 64;
        f32x4 o[4];
        #pragma unroll
        for (int t = 0; t < 4; ++t) o[t] = f32x4{0.f, 0.f, 0.f, 0.f};
        #pragma unroll
        for (int k0 = 0; k0 < 64; k0 += 32) {
            bf16x8 a = *(const bf16x8*)(Pbf + (wm + fr) * 72 + k0 + kq);
            #pragma unroll
            for (int t = 0; t < 4; ++t) {
                bf16x8 bv = *(const bf16x8*)(Vt + (wn2 + t * 16 + fr) * 72 + k0 + kq);
                o[t] = MFMA16(a, bv, o[t], 0, 0, 0);
            }
        }
        #pragma unroll
        for (int t = 0; t < 4; ++t)
            #pragma unroll
            for (int r = 0; r < 4; ++r) {
                size_t m = (size_t)b * 64 + half * 32 + wm + crow + r;
                int col = h * 128 + wn2 + t * 16 + ccol;
                x1o[m * 1024 + 512 + col] = f2bf(o[t][r]);
            }
    }
}

// ---------------------------------------------------------------------------
// Fused fc1 GEMM (blocks 0-511) + pair MLPs (blocks 512-2559).
// ---------------------------------------------------------------------------
__global__ __launch_bounds__(256)
void w1pair(const unsigned short* __restrict__ x1o,
            const unsigned short* __restrict__ W1cb,
            const float* __restrict__ beff, float* __restrict__ u,
            const unsigned short* __restrict__ Pb,
            const float* __restrict__ a1, const float* __restrict__ pws,
            const float* __restrict__ d1b1, const float* __restrict__ d1w2,
            const float* __restrict__ d1b2, const float* __restrict__ d2b1,
            const float* __restrict__ d2w2, const float* __restrict__ d2b2,
            float* __restrict__ x2_attn, float* __restrict__ out1,
            float* __restrict__ out2) {
    __shared__ unsigned short Asl[32 * 64];
    __shared__ unsigned short Bsl[64 * 64];
    const int bx = blockIdx.x, tid = threadIdx.x;
    const int wave = tid >> 6, lane = tid & 63;

    if (bx < 512) {
        const int m0 = (bx >> 3) * 32, n0 = (bx & 7) * 64;
        const int wm = (wave >> 1) * 16, wn = (wave & 1) * 32;
        const int fr = lane & 15, kq4 = lane >> 4;
        f32x4 acc[2] = {};
        for (int k0 = 0; k0 < 1024; k0 += 64) {
            {
                int r = tid >> 3, q = tid & 7;
                int col = (q ^ (r & 7)) * 8;
                __builtin_amdgcn_global_load_lds(
                    (cv_global*)(x1o + (size_t)(m0 + r) * 1024 + k0 + col),
                    (v_lds*)(Asl + wave * 512), 16, 0, 0);
            }
            #pragma unroll
            for (int c0 = 0; c0 < 512; c0 += 256) {
                int cc = c0 + tid, r = cc >> 3, q = cc & 7;
                int col = (q ^ (r & 7)) * 8;
                __builtin_amdgcn_global_load_lds(
                    (cv_global*)(W1cb + (size_t)(n0 + r) * 1024 + k0 + col),
                    (v_lds*)(Bsl + c0 * 8 + wave * 512), 16, 0, 0);
            }
            __syncthreads();
            #pragma unroll
            for (int j = 0; j < 2; ++j) {
                int kc = kq4 + j * 4;
                int rb0 = wn + fr, rb1 = wn + 16 + fr, ra = wm + fr;
                bf16x8 b0 = *(const bf16x8*)(Bsl + rb0 * 64 + (kc ^ (rb0 & 7)) * 8);
                bf16x8 b1 = *(const bf16x8*)(Bsl + rb1 * 64 + (kc ^ (rb1 & 7)) * 8);
                bf16x8 af = *(const bf16x8*)(Asl + ra * 64 + (kc ^ (ra & 7)) * 8);
                acc[0] = MFMA16(af, b0, acc[0], 0, 0, 0);
                acc[1] = MFMA16(af, b1, acc[1], 0, 0, 0);
            }
            __syncthreads();
        }
        const int crow = (lane >> 4) * 4, ccol = lane & 15;
        #pragma unroll
        for (int c = 0; c < 2; ++c) {
            int n = n0 + wn + c * 16 + ccol;
            float bj = beff[n];
            #pragma unroll
            for (int i = 0; i < 4; ++i) {
                size_t m = (size_t)(m0 + wm + crow + i);
                u[m * 512 + n] = fmaxf(acc[c][i] + bj, 0.f);
            }
        }
    } else {
        const int idx = bx - 512;
        const int f = idx & 63, b = idx >> 6;
        const size_t row = (size_t)b * SS + f;
        const int c0 = lane * 2, c1 = lane * 2 + 1;

        const float p1f0 = bf2f(Pb[row * 256 + c0]),       p1f1 = bf2f(Pb[row * 256 + c1]);
        const float p2f0 = bf2f(Pb[row * 256 + 128 + c0]), p2f1 = bf2f(Pb[row * 256 + 128 + c1]);
        const float w10 = d1w2[c0], w11 = d1w2[c1];
        const float w20 = d2w2[c0], w21 = d2w2[c1];
        const float b10 = d1b1[c0], b11 = d1b1[c1];
        const float b20 = d2b1[c0], b21 = d2b1[c1];
        const float bb1 = d1b2[0], bb2 = d2b2[0];

        const float* a1r = a1 + row * SS;
        const float* ph0 = pws + (((size_t)b * 4 + 0) * 64 + f) * 64;
        const float* ph1 = pws + (((size_t)b * 4 + 1) * 64 + f) * 64;
        const float* ph2 = pws + (((size_t)b * 4 + 2) * 64 + f) * 64;
        const float* ph3 = pws + (((size_t)b * 4 + 3) * 64 + f) * 64;
        const size_t bbase = (size_t)b * SS * 256;

        for (int g = wave; g < 64; g += 4) {
            float aa1 = a1r[g];
            float aa2 = 0.25f * (ph0[g] + ph1[g] + ph2[g] + ph3[g]);
            float q10 = bf2f(Pb[bbase + g * 256 + c0]);
            float q11 = bf2f(Pb[bbase + g * 256 + c1]);
            float q20 = bf2f(Pb[bbase + g * 256 + 128 + c0]);
            float q21 = bf2f(Pb[bbase + g * 256 + 128 + c1]);
            float h10 = fmaxf(aa1 * (q10 - p1f0) + b10, 0.f);
            float h11 = fmaxf(aa1 * (q11 - p1f1) + b11, 0.f);
            float h20 = fmaxf(aa2 * (q20 - p2f0) + b20, 0.f);
            float h21 = fmaxf(aa2 * (q21 - p2f1) + b21, 0.f);
            float s1 = w10 * h10 + w11 * h11;
            float s2 = w20 * h20 + w21 * h21;
            #pragma unroll
            for (int m = 32; m; m >>= 1) {
                s1 += __shfl_xor(s1, m);
                s2 += __shfl_xor(s2, m);
            }
            if (lane == 0) {
                x2_attn[row * SS + g] = aa2;
                out1[row * SS + g] = fmaxf(s1 + bb1, 0.f);
                out2[row * SS + g] = fmaxf(s2 + bb2, 0.f);
            }
        }
    }
}

// ---------------------------------------------------------------------------
// bf16 MFMA GEMM (BM=32), used for fc2.
// ---------------------------------------------------------------------------
__global__ __launch_bounds__(256)
void gemm_w2(const unsigned short* __restrict__ A,
             const unsigned short* __restrict__ B,
             const float* __restrict__ bias, float* __restrict__ C) {
    __shared__ unsigned short Asl[32 * 64];
    __shared__ unsigned short Bsl[64 * 64];
    const int tid = threadIdx.x, wave = tid >> 6, lane = tid & 63;
    const int m0 = blockIdx.y * 32, n0 = blockIdx.x * 64;
    const int wm = (wave >> 1) * 16, wn = (wave & 1) * 32;
    const int fr = lane & 15, kq4 = lane >> 4;
    f32x4 acc[2] = {};
    for (int k0 = 0; k0 < 512; k0 += 64) {
        {
            int r = tid >> 3, q = tid & 7;
            int col = (q ^ (r & 7)) * 8;
            __builtin_amdgcn_global_load_lds(
                (cv_global*)(A + (size_t)(m0 + r) * 512 + k0 + col),
                (v_lds*)(Asl + wave * 512), 16, 0, 0);
        }
        #pragma unroll
        for (int c0 = 0; c0 < 512; c0 += 256) {
            int cc = c0 + tid, r = cc >> 3, q = cc & 7;
            int col = (q ^ (r & 7)) * 8;
            __builtin_amdgcn_global_load_lds(
                (cv_global*)(B + (size_t)(n0 + r) * 512 + k0 + col),
                (v_lds*)(Bsl + c0 * 8 + wave * 512), 16, 0, 0);
        }
        __syncthreads();
        #pragma unroll
        for (int j = 0; j < 2; ++j) {
            int kc = kq4 + j * 4;
            int rb0 = wn + fr, rb1 = wn + 16 + fr, ra = wm + fr;
            bf16x8 b0 = *(const bf16x8*)(Bsl + rb0 * 64 + (kc ^ (rb0 & 7)) * 8);
            bf16x8 b1 = *(const bf16x8*)(Bsl + rb1 * 64 + (kc ^ (rb1 & 7)) * 8);
            bf16x8 af = *(const bf16x8*)(Asl + ra * 64 + (kc ^ (ra & 7)) * 8);
            acc[0] = MFMA16(af, b0, acc[0], 0, 0, 0);
            acc[1] = MFMA16(af, b1, acc[1], 0, 0, 0);
        }
        __syncthreads();
    }
    const int crow = (lane >> 4) * 4, ccol = lane & 15;
    #pragma unroll
    for (int c = 0; c < 2; ++c) {
        int n = n0 + wn + c * 16 + ccol;
        float bj = bias[n];
        #pragma unroll
        for (int i = 0; i < 4; ++i) {
            size_t m = (size_t)(m0 + wm + crow + i);
            C[m * 512 + n] = fmaxf(acc[c][i] + bj, 0.f);
        }
    }
}

// ---------------------------------------------------------------------------
// out = LayerNorm(base + u) * g + be (+ optional bf16 copy).
// ---------------------------------------------------------------------------
__global__ __launch_bounds__(256)
void add_ln(const float* __restrict__ base, const float* __restrict__ u,
            const float* __restrict__ gam, const float* __restrict__ bet,
            float* __restrict__ out, unsigned short* __restrict__ outb) {
    const int row = blockIdx.x;
    const int tid = threadIdx.x, wave = tid >> 6, lane = tid & 63;
    const float* br = base + (size_t)row * EE;
    const float* ur = u + (size_t)row * EE;
    float t0 = br[tid] + ur[tid];
    float t1 = br[tid + 256] + ur[tid + 256];
    float s = t0 + t1, sq = t0 * t0 + t1 * t1;
    #pragma unroll
    for (int m = 32; m; m >>= 1) {
        s += __shfl_xor(s, m);
        sq += __shfl_xor(sq, m);
    }
    __shared__ float ssum[4], ssq[4];
    if (lane == 0) { ssum[wave] = s; ssq[wave] = sq; }
    __syncthreads();
    s = ssum[0] + ssum[1] + ssum[2] + ssum[3];
    sq = ssq[0] + ssq[1] + ssq[2] + ssq[3];
    float mean = s * (1.0f / EE);
    float var = sq * (1.0f / EE) - mean * mean;
    float inv = rsqrtf(var + LNEPS);
    float v0 = (t0 - mean) * inv * gam[tid] + bet[tid];
    float v1 = (t1 - mean) * inv * gam[tid + 256] + bet[tid + 256];
    float* orow = out + (size_t)row * EE;
    orow[tid] = v0;
    orow[tid + 256] = v1;
    if (outb) {
        unsigned short* obr = outb + (size_t)row * EE;
        obr[tid] = f2bf(v0);
        obr[tid + 256] = f2bf(v1);
    }
}

// ---------------------------------------------------------------------------
extern "C" void kernel_launch(void* const* d_in, const int* in_sizes, int n_in,
                              void* d_out, int out_size, void* d_ws,
                              size_t ws_size, hipStream_t stream) {
    const float* x    = (const float*)d_in[0];
    const float* Wqkv = (const float*)d_in[1];
    const float* bqkv = (const float*)d_in[2];
    const float* Wo   = (const float*)d_in[3];
    const float* bo   = (const float*)d_in[4];
    const float* W1   = (const float*)d_in[5];
    const float* b1   = (const float*)d_in[6];
    const float* W2   = (const float*)d_in[7];
    const float* b2   = (const float*)d_in[8];
    const float* g1   = (const float*)d_in[9];
    const float* be1  = (const float*)d_in[10];
    const float* g2   = (const float*)d_in[11];
    const float* be2  = (const float*)d_in[12];
    const float* d1W1 = (const float*)d_in[13];
    const float* d1b1 = (const float*)d_in[14];
    const float* d1W2 = (const float*)d_in[15];
    const float* d1b2 = (const float*)d_in[16];
    const float* d2W1 = (const float*)d_in[17];
    const float* d2b1 = (const float*)d_in[18];
    const float* d2W2 = (const float*)d_in[19];
    const float* d2b2 = (const float*)d_in[20];

    float* out      = (float*)d_out;
    float* out_main = out;
    float* x1_attn  = out + 1048576;
    float* x2_attn  = out + 1048576 + 131072;
    float* diff1    = out + 1048576 + 2 * 131072;
    float* diff2    = out + 1048576 + 3 * 131072;

    float* ws    = (float*)d_ws;
    float* u_buf = ws;                              // 2048*512
    float* h_buf = ws + 1048576;                    // 2048*512
    float* pws   = ws + 2097152;                    // 32*4*64*64
    float* b_eff = ws + 2621440;                    // 512
    unsigned short* Pl2 = (unsigned short*)(ws + 2621952);  // 2048*64 bf16
    unsigned short* bb  = (unsigned short*)(ws + 2687488);

    unsigned short* xb    = bb + XB_O;
    unsigned short* Wfull = bb + WFULL_O;
    unsigned short* W1cb  = bb + W1CB_O;
    unsigned short* W2b   = bb + W2B_O;
    unsigned short* qkvb  = bb + QKVB_O;
    unsigned short* x1o   = bb + X1O_O;
    unsigned short* hb    = bb + HB_O;
    unsigned short* Pb    = bb + PB_O;

    // 1: convert + Wc prep + b_eff + Gram L2-attention (input-only deps)
    mega1<<<1508, 256, 0, stream>>>(x, Wqkv, Wo, W1, W2, d1W1, d2W1, b1, bo,
                                    bb, b_eff, x1_attn, Pl2);

    // 2: [qkv | P] = xb @ Wfull^T  +  x1 = Pl2 @ xb  (x1 -> x1o[:, :512])
    gemm_qkvp<<<dim3(36, 32), 256, 0, stream>>>(xb, Wfull, bqkv, qkvb, Pb,
                                                Pl2, x1o);

    // 3: attention; o -> x1o[:,512:], probs -> pws
    mha_attn<<<dim3(8, 32), 256, 0, stream>>>(qkvb, x1o, pws);

    // 4: u = relu([x1|o] @ [W1a|Wc]^T + b_eff)  +  pair MLPs
    w1pair<<<2560, 256, 0, stream>>>(x1o, W1cb, b_eff, u_buf, Pb, x1_attn, pws,
                                     d1b1, d1W2, d1b2, d2b1, d2W2, d2b2,
                                     x2_attn, diff1, diff2);

    // 5: h = LN(x + u) -> h_buf (f32) + hb (bf16)
    add_ln<<<2048, 256, 0, stream>>>(x, u_buf, g1, be1, h_buf, hb);

    // 6: u = relu(h @ W2^T + b2)
    gemm_w2<<<dim3(8, 64), 256, 0, stream>>>(hb, W2b, b2, u_buf);

    // 7: out = LN(h + u)
    add_ln<<<2048, 256, 0, stream>>>(h_buf, u_buf, g2, be2, out_main, nullptr);
}